// Round 1
// baseline (8213.784 us; speedup 1.0000x reference)
//
#include <hip/hip_runtime.h>
#include <math.h>

#define Tn 4096   // B*S tokens
#define Dn 2048   // hidden
#define Sn 2048   // seq
#define Hn 16     // heads
#define Fn 8192   // ffn
#define Rn 32     // adapter rank

__device__ __forceinline__ float gelu_f(float x) {
  return 0.5f * x * (1.0f + tanhf(0.7978845608028654f * (x + 0.044715f * x * x * x)));
}

// ---------------- fused LayerNorm (+ optional router argmax) ----------------
// one block per token row of 2048; 256 threads * 8 elems
__global__ __launch_bounds__(256)
void ln_router_kernel(const float* __restrict__ x,
                      const float* __restrict__ sc,
                      const float* __restrict__ bi,
                      const float* __restrict__ wr,   // [3,D] or nullptr
                      float* __restrict__ xn,
                      int* __restrict__ dec)          // [T] or nullptr
{
  const int t = blockIdx.x;
  const int tid = threadIdx.x;
  const float* row = x + (size_t)t * Dn;
  const int d0 = tid * 8;
  float4 v0 = *(const float4*)(row + d0);
  float4 v1 = *(const float4*)(row + d0 + 4);
  float a[5];
  a[0] = v0.x + v0.y + v0.z + v0.w + v1.x + v1.y + v1.z + v1.w;
  a[1] = v0.x*v0.x + v0.y*v0.y + v0.z*v0.z + v0.w*v0.w
       + v1.x*v1.x + v1.y*v1.y + v1.z*v1.z + v1.w*v1.w;
  a[2] = 0.f; a[3] = 0.f; a[4] = 0.f;
  if (wr) {
#pragma unroll
    for (int r = 0; r < 3; ++r) {
      float4 w0 = *(const float4*)(wr + r * Dn + d0);
      float4 w1 = *(const float4*)(wr + r * Dn + d0 + 4);
      a[2 + r] = v0.x*w0.x + v0.y*w0.y + v0.z*w0.z + v0.w*w0.w
               + v1.x*w1.x + v1.y*w1.y + v1.z*w1.z + v1.w*w1.w;
    }
  }
#pragma unroll
  for (int i = 0; i < 5; ++i) {
#pragma unroll
    for (int off = 32; off > 0; off >>= 1)
      a[i] += __shfl_down(a[i], off);
  }
  __shared__ float red[4][5];
  __shared__ float fin[5];
  const int wv = tid >> 6, ln = tid & 63;
  if (ln == 0) {
#pragma unroll
    for (int i = 0; i < 5; ++i) red[wv][i] = a[i];
  }
  __syncthreads();
  if (tid == 0) {
#pragma unroll
    for (int i = 0; i < 5; ++i)
      fin[i] = red[0][i] + red[1][i] + red[2][i] + red[3][i];
    if (dec) {
      float l0 = fin[2], l1 = fin[3], l2 = fin[4];
      int best = 0; float bl = l0;
      if (l1 > bl) { best = 1; bl = l1; }   // first-max semantics like jnp.argmax
      if (l2 > bl) { best = 2; }
      dec[t] = best;
    }
  }
  __syncthreads();
  const float mu  = fin[0] * (1.0f / Dn);
  const float var = fin[1] * (1.0f / Dn) - mu * mu;
  const float rs  = rsqrtf(var + 1e-5f);
  float4 s0 = *(const float4*)(sc + d0);
  float4 s1 = *(const float4*)(sc + d0 + 4);
  float4 b0 = *(const float4*)(bi + d0);
  float4 b1 = *(const float4*)(bi + d0 + 4);
  float4 o0, o1;
  o0.x = (v0.x - mu) * rs * s0.x + b0.x;
  o0.y = (v0.y - mu) * rs * s0.y + b0.y;
  o0.z = (v0.z - mu) * rs * s0.z + b0.z;
  o0.w = (v0.w - mu) * rs * s0.w + b0.w;
  o1.x = (v1.x - mu) * rs * s1.x + b1.x;
  o1.y = (v1.y - mu) * rs * s1.y + b1.y;
  o1.z = (v1.z - mu) * rs * s1.z + b1.z;
  o1.w = (v1.w - mu) * rs * s1.w + b1.w;
  *(float4*)(xn + (size_t)t * Dn + d0)     = o0;
  *(float4*)(xn + (size_t)t * Dn + d0 + 4) = o1;
}

// ---------------- generic NT GEMM: C = A[M,K] @ B[N,K]^T (+resid)(+acc)(gelu) ----
// 128x128 tile, BK=16, 256 threads, 8x8 microtile
#define GBM 128
#define GBN 128
#define GBK 16
__global__ __launch_bounds__(256)
void gemm_nt(const float* __restrict__ A, int lda,
             const float* __restrict__ B, int ldb,
             float* __restrict__ C, int ldc,
             const float* __restrict__ resid,
             int M, int N, int K, int flags)   // flags: 1=gelu, 2=accumulate into C
{
  __shared__ float As[GBK][GBM + 4];
  __shared__ float Bs[GBK][GBN + 4];
  const int bm = blockIdx.y * GBM;
  const int bn = blockIdx.x * GBN;
  const int tid = threadIdx.x;
  const int ty = tid >> 4, tx = tid & 15;
  float acc[8][8];
#pragma unroll
  for (int i = 0; i < 8; ++i)
#pragma unroll
    for (int j = 0; j < 8; ++j) acc[i][j] = 0.f;

  for (int k0 = 0; k0 < K; k0 += GBK) {
#pragma unroll
    for (int i = 0; i < 2; ++i) {
      int fid = tid + i * 256;              // 512 float4 per operand tile
      int row = fid >> 2, c = (fid & 3) << 2;
      float4 av = *(const float4*)(A + (size_t)(bm + row) * lda + k0 + c);
      As[c + 0][row] = av.x; As[c + 1][row] = av.y;
      As[c + 2][row] = av.z; As[c + 3][row] = av.w;
      float4 bv = make_float4(0.f, 0.f, 0.f, 0.f);
      if (bn + row < N)
        bv = *(const float4*)(B + (size_t)(bn + row) * ldb + k0 + c);
      Bs[c + 0][row] = bv.x; Bs[c + 1][row] = bv.y;
      Bs[c + 2][row] = bv.z; Bs[c + 3][row] = bv.w;
    }
    __syncthreads();
#pragma unroll
    for (int k = 0; k < GBK; ++k) {
      float4 a0 = *(const float4*)&As[k][ty * 4];
      float4 a1 = *(const float4*)&As[k][64 + ty * 4];
      float4 b0 = *(const float4*)&Bs[k][tx * 4];
      float4 b1 = *(const float4*)&Bs[k][64 + tx * 4];
      float aa[8] = {a0.x, a0.y, a0.z, a0.w, a1.x, a1.y, a1.z, a1.w};
      float bb[8] = {b0.x, b0.y, b0.z, b0.w, b1.x, b1.y, b1.z, b1.w};
#pragma unroll
      for (int i = 0; i < 8; ++i)
#pragma unroll
        for (int j = 0; j < 8; ++j)
          acc[i][j] += aa[i] * bb[j];
    }
    __syncthreads();
  }
  // epilogue
#pragma unroll
  for (int i = 0; i < 8; ++i) {
    int row = bm + ((i < 4) ? (ty * 4 + i) : (64 + ty * 4 + i - 4));
#pragma unroll
    for (int jj = 0; jj < 2; ++jj) {
      int col = bn + ((jj == 0) ? (tx * 4) : (64 + tx * 4));
      if (col < N) {
        float4 o;
        o.x = acc[i][jj * 4 + 0]; o.y = acc[i][jj * 4 + 1];
        o.z = acc[i][jj * 4 + 2]; o.w = acc[i][jj * 4 + 3];
        if (flags & 1) { o.x = gelu_f(o.x); o.y = gelu_f(o.y); o.z = gelu_f(o.z); o.w = gelu_f(o.w); }
        size_t cidx = (size_t)row * ldc + col;
        if (resid) {
          float4 rv = *(const float4*)(resid + cidx);
          o.x += rv.x; o.y += rv.y; o.z += rv.z; o.w += rv.w;
        }
        if (flags & 2) {
          float4 cv = *(const float4*)(C + cidx);
          o.x += cv.x; o.y += cv.y; o.z += cv.z; o.w += cv.w;
        }
        *(float4*)(C + cidx) = o;
      }
    }
  }
}

// ---------------- causal flash attention, fp32 ----------------
// grid (S/32, B*H); 256 thr = 16 groups x 16 lanes; group handles 2 q rows;
// lane x owns dims x*8..x*8+7
__global__ __launch_bounds__(256)
void attn_kernel(const float* __restrict__ Qb, const float* __restrict__ Kb,
                 const float* __restrict__ Vb, float* __restrict__ Ctx)
{
  const int bh = blockIdx.y;
  const int b = bh >> 4, h = bh & 15;
  const int q0 = blockIdx.x * 32;
  const int g = threadIdx.x >> 4;
  const int x = threadIdx.x & 15;
  const float scl = 0.08838834764831845f;  // 1/sqrt(128)
  const size_t base = (size_t)b * Sn * Dn + (size_t)h * 128;
  const float* Q = Qb + base;
  const float* K = Kb + base;
  const float* V = Vb + base;
  const int s0 = q0 + 2 * g, s1 = s0 + 1;

  float q0r[8], q1r[8], c0[8], c1[8];
  {
    float4 qa = *(const float4*)&Q[(size_t)s0 * Dn + x * 8];
    float4 qb = *(const float4*)&Q[(size_t)s0 * Dn + x * 8 + 4];
    float4 qc = *(const float4*)&Q[(size_t)s1 * Dn + x * 8];
    float4 qd = *(const float4*)&Q[(size_t)s1 * Dn + x * 8 + 4];
    q0r[0]=qa.x*scl; q0r[1]=qa.y*scl; q0r[2]=qa.z*scl; q0r[3]=qa.w*scl;
    q0r[4]=qb.x*scl; q0r[5]=qb.y*scl; q0r[6]=qb.z*scl; q0r[7]=qb.w*scl;
    q1r[0]=qc.x*scl; q1r[1]=qc.y*scl; q1r[2]=qc.z*scl; q1r[3]=qc.w*scl;
    q1r[4]=qd.x*scl; q1r[5]=qd.y*scl; q1r[6]=qd.z*scl; q1r[7]=qd.w*scl;
  }
#pragma unroll
  for (int i = 0; i < 8; ++i) { c0[i] = 0.f; c1[i] = 0.f; }
  float m0 = -1e30f, m1 = -1e30f, l0a = 0.f, l1a = 0.f;
  __shared__ float Ks[32][128];
  __shared__ float Vs[32][128];

  for (int j0 = 0; j0 < q0 + 32; j0 += 32) {
    for (int u = threadIdx.x; u < 1024; u += 256) {
      int r = u >> 5, c4 = (u & 31) << 2;
      *(float4*)&Ks[r][c4] = *(const float4*)&K[(size_t)(j0 + r) * Dn + c4];
      *(float4*)&Vs[r][c4] = *(const float4*)&V[(size_t)(j0 + r) * Dn + c4];
    }
    __syncthreads();
    float p0[32], p1[32];
    float mt0 = m0, mt1 = m1;
#pragma unroll
    for (int j = 0; j < 32; ++j) {
      float4 kv0 = *(const float4*)&Ks[j][x * 8];
      float4 kv1 = *(const float4*)&Ks[j][x * 8 + 4];
      float pa = q0r[0]*kv0.x + q0r[1]*kv0.y + q0r[2]*kv0.z + q0r[3]*kv0.w
               + q0r[4]*kv1.x + q0r[5]*kv1.y + q0r[6]*kv1.z + q0r[7]*kv1.w;
      float pb = q1r[0]*kv0.x + q1r[1]*kv0.y + q1r[2]*kv0.z + q1r[3]*kv0.w
               + q1r[4]*kv1.x + q1r[5]*kv1.y + q1r[6]*kv1.z + q1r[7]*kv1.w;
#pragma unroll
      for (int mm = 8; mm > 0; mm >>= 1) {
        pa += __shfl_xor(pa, mm, 16);
        pb += __shfl_xor(pb, mm, 16);
      }
      int jj = j0 + j;
      pa = (jj <= s0) ? pa : -1e30f;
      pb = (jj <= s1) ? pb : -1e30f;
      p0[j] = pa; p1[j] = pb;
      mt0 = fmaxf(mt0, pa); mt1 = fmaxf(mt1, pb);
    }
    float cor0 = __expf(m0 - mt0), cor1 = __expf(m1 - mt1);
    l0a *= cor0; l1a *= cor1;
#pragma unroll
    for (int i = 0; i < 8; ++i) { c0[i] *= cor0; c1[i] *= cor1; }
#pragma unroll
    for (int j = 0; j < 32; ++j) {
      float w0 = __expf(p0[j] - mt0);
      float w1 = __expf(p1[j] - mt1);
      l0a += w0; l1a += w1;
      float4 vv0 = *(const float4*)&Vs[j][x * 8];
      float4 vv1 = *(const float4*)&Vs[j][x * 8 + 4];
      c0[0] += w0*vv0.x; c0[1] += w0*vv0.y; c0[2] += w0*vv0.z; c0[3] += w0*vv0.w;
      c0[4] += w0*vv1.x; c0[5] += w0*vv1.y; c0[6] += w0*vv1.z; c0[7] += w0*vv1.w;
      c1[0] += w1*vv0.x; c1[1] += w1*vv0.y; c1[2] += w1*vv0.z; c1[3] += w1*vv0.w;
      c1[4] += w1*vv1.x; c1[5] += w1*vv1.y; c1[6] += w1*vv1.z; c1[7] += w1*vv1.w;
    }
    m0 = mt0; m1 = mt1;
    __syncthreads();
  }
  const float inv0 = 1.0f / l0a, inv1 = 1.0f / l1a;
  float4 o;
  o.x = c0[0]*inv0; o.y = c0[1]*inv0; o.z = c0[2]*inv0; o.w = c0[3]*inv0;
  *(float4*)&Ctx[base + (size_t)s0 * Dn + x * 8] = o;
  o.x = c0[4]*inv0; o.y = c0[5]*inv0; o.z = c0[6]*inv0; o.w = c0[7]*inv0;
  *(float4*)&Ctx[base + (size_t)s0 * Dn + x * 8 + 4] = o;
  o.x = c1[0]*inv1; o.y = c1[1]*inv1; o.z = c1[2]*inv1; o.w = c1[3]*inv1;
  *(float4*)&Ctx[base + (size_t)s1 * Dn + x * 8] = o;
  o.x = c1[4]*inv1; o.y = c1[5]*inv1; o.z = c1[6]*inv1; o.w = c1[7]*inv1;
  *(float4*)&Ctx[base + (size_t)s1 * Dn + x * 8 + 4] = o;
}

// ---------------- final per-token routing select ----------------
__global__ __launch_bounds__(256)
void select_kernel(const float* __restrict__ h, const float* __restrict__ bias,
                   const float* __restrict__ out1, const float* __restrict__ out2,
                   const int* __restrict__ dec, float* __restrict__ out)
{
  int i = blockIdx.x * 256 + threadIdx.x;     // float4 index
  if (i >= Tn * Dn / 4) return;
  int t = i >> 9;                              // / (2048/4)
  int d4 = (i & 511) << 2;
  size_t idx = (size_t)t * Dn + d4;
  int de = dec[t];
  float4 o;
  if (de == 0) {
    float4 hv = *(const float4*)(h + idx);
    float4 bv = *(const float4*)(bias + d4);
    o.x = hv.x + bv.x; o.y = hv.y + bv.y; o.z = hv.z + bv.z; o.w = hv.w + bv.w;
  } else if (de == 1) {
    o = *(const float4*)(out1 + idx);
  } else {
    o = *(const float4*)(out2 + idx);
  }
  *(float4*)((float*)out + idx) = o;
}

extern "C" void kernel_launch(void* const* d_in, const int* in_sizes, int n_in,
                              void* d_out, int out_size, void* d_ws, size_t ws_size,
                              hipStream_t stream) {
  const float* hid    = (const float*)d_in[0];
  const float* sbias  = (const float*)d_in[1];
  const float* w_down = (const float*)d_in[2];
  const float* w_up   = (const float*)d_in[3];
  const float* w_rout = (const float*)d_in[4];
  const float* ln1s   = (const float*)d_in[5];
  const float* ln1b   = (const float*)d_in[6];
  const float* wq     = (const float*)d_in[7];
  const float* wk     = (const float*)d_in[8];
  const float* wv     = (const float*)d_in[9];
  const float* wo     = (const float*)d_in[10];
  const float* ln2s   = (const float*)d_in[11];
  const float* ln2b   = (const float*)d_in[12];
  const float* w_ff1  = (const float*)d_in[13];
  const float* w_ff2  = (const float*)d_in[14];

  const size_t TD = (size_t)Tn * Dn;
  float* ws   = (float*)d_ws;
  float* xn   = ws;            // LN1 out; later ctx; later FFN chunk buffer
  float* qb   = xn + TD;       // Q; later xn2
  float* kb   = qb + TD;       // K; later out2
  float* vb   = kb + TD;       // V; later out1
  float* x2   = vb + TD;       // attn residual output
  float* hd   = x2 + TD;       // [T,R] adapter hidden
  int*   dec  = (int*)(hd + (size_t)Tn * Rn);
  size_t need = (5 * TD + (size_t)Tn * Rn) * 4 + (size_t)Tn * 4;
  if (ws_size < need) return;  // insufficient scratch: fail loudly (wrong output, no corruption)

  dim3 gq(Dn / GBN, Tn / GBM);

  // 1. LN1 + router decisions (router on RAW hidden)
  ln_router_kernel<<<Tn, 256, 0, stream>>>(hid, ln1s, ln1b, w_rout, xn, dec);
  // 2. Q,K,V = xn @ w{q,k,v}.T
  gemm_nt<<<gq, 256, 0, stream>>>(xn, Dn, wq, Dn, qb, Dn, nullptr, Tn, Dn, Dn, 0);
  gemm_nt<<<gq, 256, 0, stream>>>(xn, Dn, wk, Dn, kb, Dn, nullptr, Tn, Dn, Dn, 0);
  gemm_nt<<<gq, 256, 0, stream>>>(xn, Dn, wv, Dn, vb, Dn, nullptr, Tn, Dn, Dn, 0);
  // 3. causal attention → ctx (into xn, Q/K/V no longer need xn)
  attn_kernel<<<dim3(Sn / 32, 2 * Hn), 256, 0, stream>>>(qb, kb, vb, xn);
  // 4. x2 = hid + ctx @ wo.T
  gemm_nt<<<gq, 256, 0, stream>>>(xn, Dn, wo, Dn, x2, Dn, hid, Tn, Dn, Dn, 0);
  // 5. xn2 = LN2(x2) (into qb)
  ln_router_kernel<<<Tn, 256, 0, stream>>>(x2, ln2s, ln2b, nullptr, qb, nullptr);
  // 6. FFN chunked over F (chunk buffer = xn): out2 (kb) = x2 + gelu(xn2@w_ff1.T)@w_ff2.T
  for (int f0 = 0; f0 < Fn; f0 += Dn) {
    gemm_nt<<<gq, 256, 0, stream>>>(qb, Dn, w_ff1 + (size_t)f0 * Dn, Dn,
                                    xn, Dn, nullptr, Tn, Dn, Dn, 1 /*gelu*/);
    gemm_nt<<<gq, 256, 0, stream>>>(xn, Dn, w_ff2 + f0, Fn, kb, Dn,
                                    (f0 == 0) ? x2 : nullptr, Tn, Dn, Dn,
                                    (f0 == 0) ? 0 : 2 /*accumulate*/);
  }
  // 7. adapter: hd = hid @ w_down.T; out1 (vb) = hid + hd @ w_up.T
  gemm_nt<<<dim3(1, Tn / GBM), 256, 0, stream>>>(hid, Dn, w_down, Dn, hd, Rn, nullptr, Tn, Rn, Dn, 0);
  gemm_nt<<<gq, 256, 0, stream>>>(hd, Rn, w_up, Rn, vb, Dn, hid, Tn, Dn, Rn, 0);
  // 8. routing select
  int nv4 = Tn * Dn / 4;
  select_kernel<<<(nv4 + 255) / 256, 256, 0, stream>>>(hid, sbias, vb, kb, dec, (float*)d_out);
}

// Round 4
// 4000.148 us; speedup vs baseline: 2.0534x; 2.0534x over previous
//
#include <hip/hip_runtime.h>
#include <math.h>

#define Tn 4096   // B*S tokens
#define Dn 2048   // hidden
#define Sn 2048   // seq
#define Hn 16     // heads
#define Fn 8192   // ffn
#define Rn 32     // adapter rank
#define FC 2048   // ffn chunk size

typedef short bf16x8 __attribute__((ext_vector_type(8)));
typedef float f32x4 __attribute__((ext_vector_type(4)));

union U8 { unsigned short s[8]; uint4 v; };

__device__ __forceinline__ float gelu_f(float x) {
  return 0.5f * x * (1.0f + tanhf(0.7978845608028654f * (x + 0.044715f * x * x * x)));
}

__device__ __forceinline__ unsigned short f2bf(float x) {   // RNE
  union { float f; unsigned u; } v; v.f = x;
  unsigned r = v.u + 0x7FFFu + ((v.u >> 16) & 1u);
  return (unsigned short)(r >> 16);
}
__device__ __forceinline__ float bf2f(unsigned short h) {
  union { unsigned u; float f; } v; v.u = ((unsigned)h) << 16; return v.f;
}

__device__ __forceinline__ void glds16(const unsigned short* g, unsigned short* lds) {
  // async global->LDS, 16B per lane; LDS dest is wave-uniform base (HW adds lane*16)
  __builtin_amdgcn_global_load_lds((const __attribute__((address_space(1))) void*)g,
                                   (__attribute__((address_space(3))) void*)lds, 16, 0, 0);
}

// ---------------- fused LayerNorm (+ optional router argmax), bf16 hi/lo output --------
__global__ __launch_bounds__(256)
void ln_router_kernel(const float* __restrict__ x,
                      const float* __restrict__ sc,
                      const float* __restrict__ bi,
                      const float* __restrict__ wr,       // [3,D] or nullptr
                      unsigned short* __restrict__ xh,    // [T,D] bf16 hi
                      unsigned short* __restrict__ xl,    // [T,D] bf16 lo
                      int* __restrict__ dec)              // [T] or nullptr
{
  const int t = blockIdx.x;
  const int tid = threadIdx.x;
  const float* row = x + (size_t)t * Dn;
  const int d0 = tid * 8;
  float4 v0 = *(const float4*)(row + d0);
  float4 v1 = *(const float4*)(row + d0 + 4);
  float a[5];
  a[0] = v0.x + v0.y + v0.z + v0.w + v1.x + v1.y + v1.z + v1.w;
  a[1] = v0.x*v0.x + v0.y*v0.y + v0.z*v0.z + v0.w*v0.w
       + v1.x*v1.x + v1.y*v1.y + v1.z*v1.z + v1.w*v1.w;
  a[2] = 0.f; a[3] = 0.f; a[4] = 0.f;
  if (wr) {
#pragma unroll
    for (int r = 0; r < 3; ++r) {
      float4 w0 = *(const float4*)(wr + r * Dn + d0);
      float4 w1 = *(const float4*)(wr + r * Dn + d0 + 4);
      a[2 + r] = v0.x*w0.x + v0.y*w0.y + v0.z*w0.z + v0.w*w0.w
               + v1.x*w1.x + v1.y*w1.y + v1.z*w1.z + v1.w*w1.w;
    }
  }
#pragma unroll
  for (int i = 0; i < 5; ++i) {
#pragma unroll
    for (int off = 32; off > 0; off >>= 1)
      a[i] += __shfl_down(a[i], off);
  }
  __shared__ float red[4][5];
  __shared__ float fin[5];
  const int wv = tid >> 6, ln = tid & 63;
  if (ln == 0) {
#pragma unroll
    for (int i = 0; i < 5; ++i) red[wv][i] = a[i];
  }
  __syncthreads();
  if (tid == 0) {
#pragma unroll
    for (int i = 0; i < 5; ++i)
      fin[i] = red[0][i] + red[1][i] + red[2][i] + red[3][i];
    if (dec) {
      float l0 = fin[2], l1 = fin[3], l2 = fin[4];
      int best = 0; float bl = l0;
      if (l1 > bl) { best = 1; bl = l1; }
      if (l2 > bl) { best = 2; }
      dec[t] = best;
    }
  }
  __syncthreads();
  const float mu  = fin[0] * (1.0f / Dn);
  const float var = fin[1] * (1.0f / Dn) - mu * mu;
  const float rs  = rsqrtf(var + 1e-5f);
  float4 s0 = *(const float4*)(sc + d0);
  float4 s1 = *(const float4*)(sc + d0 + 4);
  float4 b0 = *(const float4*)(bi + d0);
  float4 b1 = *(const float4*)(bi + d0 + 4);
  float o[8];
  o[0] = (v0.x - mu) * rs * s0.x + b0.x;
  o[1] = (v0.y - mu) * rs * s0.y + b0.y;
  o[2] = (v0.z - mu) * rs * s0.z + b0.z;
  o[3] = (v0.w - mu) * rs * s0.w + b0.w;
  o[4] = (v1.x - mu) * rs * s1.x + b1.x;
  o[5] = (v1.y - mu) * rs * s1.y + b1.y;
  o[6] = (v1.z - mu) * rs * s1.z + b1.z;
  o[7] = (v1.w - mu) * rs * s1.w + b1.w;
  U8 hu, lu;
#pragma unroll
  for (int j = 0; j < 8; ++j) {
    hu.s[j] = f2bf(o[j]);
    lu.s[j] = f2bf(o[j] - bf2f(hu.s[j]));
  }
  *(uint4*)&xh[(size_t)t * Dn + d0] = hu.v;
  *(uint4*)&xl[(size_t)t * Dn + d0] = lu.v;
}

// ---------------- fp32 -> bf16 hi/lo pair (weights) ----------------
// src [rows][K] with row-stride ld; output packed [rows][K]
__global__ __launch_bounds__(256)
void cvt_pair_kernel(const float* __restrict__ src, int ld, int K,
                     unsigned short* __restrict__ H, unsigned short* __restrict__ L,
                     int total8)
{
  int i = blockIdx.x * 256 + threadIdx.x;
  if (i >= total8) return;
  size_t e = (size_t)i * 8;
  int row = (int)(e / (size_t)K);
  int col = (int)(e % (size_t)K);
  const float* s = src + (size_t)row * ld + col;
  float4 v0 = *(const float4*)s;
  float4 v1 = *(const float4*)(s + 4);
  float o[8] = {v0.x, v0.y, v0.z, v0.w, v1.x, v1.y, v1.z, v1.w};
  U8 hu, lu;
#pragma unroll
  for (int j = 0; j < 8; ++j) {
    hu.s[j] = f2bf(o[j]);
    lu.s[j] = f2bf(o[j] - bf2f(hu.s[j]));
  }
  *(uint4*)&H[e] = hu.v;
  *(uint4*)&L[e] = lu.v;
}

// ---------------- split-bf16 MFMA GEMM: C = (Ah+Al)[M,K] @ (Bh+Bl)[N,K]^T ----------------
// 128x128 tile, BK=32, 256 thr = 4 waves (2x2), each wave 64x64 = 4x4 16x16x32 fragments.
// mode 0: C = acc (+resid); mode 2: C += acc; mode 1: (Gh,Gl) = split(gelu(acc))
#define BM 128
#define BN 128
#define BK 32
__global__ __launch_bounds__(256)
void gemm_bf16s(const unsigned short* __restrict__ Ah, const unsigned short* __restrict__ Al,
                const unsigned short* __restrict__ Bh, const unsigned short* __restrict__ Bl,
                int K, float* __restrict__ C, const float* __restrict__ resid,
                unsigned short* __restrict__ Gh, unsigned short* __restrict__ Gl,
                int N, int mode)
{
  __shared__ unsigned short sAh[BM * BK];
  __shared__ unsigned short sAl[BM * BK];
  __shared__ unsigned short sBh[BN * BK];
  __shared__ unsigned short sBl[BN * BK];
  const int tid = threadIdx.x;
  const int l = tid & 63, w = tid >> 6;
  const int wm = w >> 1, wn = w & 1;
  const int fr = l & 15, kg = (l >> 4) * 8;
  const int bm = blockIdx.y * BM, bn = blockIdx.x * BN;

  f32x4 acc[4][4];
#pragma unroll
  for (int m = 0; m < 4; ++m)
#pragma unroll
    for (int n = 0; n < 4; ++n)
#pragma unroll
      for (int q = 0; q < 4; ++q) acc[m][n][q] = 0.f;

  for (int k0 = 0; k0 < K; k0 += BK) {
    // stage 4 tiles of [128][32] bf16 via global_load_lds (16B/lane)
#pragma unroll
    for (int r = 0; r < 2; ++r) {
      const int c = r * 256 + tid;            // chunk id = row*4 + quad
      const int row = c >> 2, q = c & 3;
      const size_t ga = (size_t)(bm + row) * K + k0 + q * 8;
      const size_t gb = (size_t)(bn + row) * K + k0 + q * 8;
      const int ub = (r * 256 + w * 64) * 8;  // wave-uniform LDS base (ushorts)
      glds16(Ah + ga, sAh + ub);
      glds16(Al + ga, sAl + ub);
      glds16(Bh + gb, sBh + ub);
      glds16(Bl + gb, sBl + ub);
    }
    __syncthreads();   // compiler drains vmcnt before s_barrier -> tiles visible

    bf16x8 ah[4], al[4], bh[4], bl[4];
#pragma unroll
    for (int m = 0; m < 4; ++m) {
      const int ro = (wm * 64 + m * 16 + fr) * BK + kg;
      ah[m] = *(const bf16x8*)&sAh[ro];
      al[m] = *(const bf16x8*)&sAl[ro];
    }
#pragma unroll
    for (int n = 0; n < 4; ++n) {
      const int ro = (wn * 64 + n * 16 + fr) * BK + kg;
      bh[n] = *(const bf16x8*)&sBh[ro];
      bl[n] = *(const bf16x8*)&sBl[ro];
    }
#pragma unroll
    for (int m = 0; m < 4; ++m)
#pragma unroll
      for (int n = 0; n < 4; ++n) {
        acc[m][n] = __builtin_amdgcn_mfma_f32_16x16x32_bf16(ah[m], bh[n], acc[m][n], 0, 0, 0);
        acc[m][n] = __builtin_amdgcn_mfma_f32_16x16x32_bf16(ah[m], bl[n], acc[m][n], 0, 0, 0);
        acc[m][n] = __builtin_amdgcn_mfma_f32_16x16x32_bf16(al[m], bh[n], acc[m][n], 0, 0, 0);
      }
    __syncthreads();
  }

  // epilogue: C/D layout col=lane&15, row=(lane>>4)*4+i  [m89/m91-verified]
  const int rbase = (l >> 4) * 4;
#pragma unroll
  for (int m = 0; m < 4; ++m) {
#pragma unroll
    for (int i = 0; i < 4; ++i) {
      const int row = bm + wm * 64 + m * 16 + rbase + i;
#pragma unroll
      for (int n = 0; n < 4; ++n) {
        const int col = bn + wn * 64 + n * 16 + fr;
        float v = acc[m][n][i];
        const size_t idx = (size_t)row * N + col;
        if (mode == 1) {
          float g = gelu_f(v);
          unsigned short h = f2bf(g);
          Gh[idx] = h;
          Gl[idx] = f2bf(g - bf2f(h));
        } else {
          if (resid) v += resid[idx];
          if (mode == 2) v += C[idx];
          C[idx] = v;
        }
      }
    }
  }
}

// ---------------- fp32 vector GEMM (adapter only: tiny K or N) ----------------
#define GBM 128
#define GBN 128
#define GBK 16
__global__ __launch_bounds__(256)
void gemm_nt(const float* __restrict__ A, int lda,
             const float* __restrict__ B, int ldb,
             float* __restrict__ C, int ldc,
             const float* __restrict__ resid,
             int M, int N, int K, int flags)
{
  __shared__ float As[GBK][GBM + 4];
  __shared__ float Bs[GBK][GBN + 4];
  const int bm = blockIdx.y * GBM;
  const int bn = blockIdx.x * GBN;
  const int tid = threadIdx.x;
  const int ty = tid >> 4, tx = tid & 15;
  float acc[8][8];
#pragma unroll
  for (int i = 0; i < 8; ++i)
#pragma unroll
    for (int j = 0; j < 8; ++j) acc[i][j] = 0.f;

  for (int k0 = 0; k0 < K; k0 += GBK) {
#pragma unroll
    for (int i = 0; i < 2; ++i) {
      int fid = tid + i * 256;
      int row = fid >> 2, c = (fid & 3) << 2;
      float4 av = *(const float4*)(A + (size_t)(bm + row) * lda + k0 + c);
      As[c + 0][row] = av.x; As[c + 1][row] = av.y;
      As[c + 2][row] = av.z; As[c + 3][row] = av.w;
      float4 bv = make_float4(0.f, 0.f, 0.f, 0.f);
      if (bn + row < N)
        bv = *(const float4*)(B + (size_t)(bn + row) * ldb + k0 + c);
      Bs[c + 0][row] = bv.x; Bs[c + 1][row] = bv.y;
      Bs[c + 2][row] = bv.z; Bs[c + 3][row] = bv.w;
    }
    __syncthreads();
#pragma unroll
    for (int k = 0; k < GBK; ++k) {
      float4 a0 = *(const float4*)&As[k][ty * 4];
      float4 a1 = *(const float4*)&As[k][64 + ty * 4];
      float4 b0 = *(const float4*)&Bs[k][tx * 4];
      float4 b1 = *(const float4*)&Bs[k][64 + tx * 4];
      float aa[8] = {a0.x, a0.y, a0.z, a0.w, a1.x, a1.y, a1.z, a1.w};
      float bb[8] = {b0.x, b0.y, b0.z, b0.w, b1.x, b1.y, b1.z, b1.w};
#pragma unroll
      for (int i = 0; i < 8; ++i)
#pragma unroll
        for (int j = 0; j < 8; ++j)
          acc[i][j] += aa[i] * bb[j];
    }
    __syncthreads();
  }
#pragma unroll
  for (int i = 0; i < 8; ++i) {
    int row = bm + ((i < 4) ? (ty * 4 + i) : (64 + ty * 4 + i - 4));
#pragma unroll
    for (int jj = 0; jj < 2; ++jj) {
      int col = bn + ((jj == 0) ? (tx * 4) : (64 + tx * 4));
      if (col < N) {
        float4 o;
        o.x = acc[i][jj * 4 + 0]; o.y = acc[i][jj * 4 + 1];
        o.z = acc[i][jj * 4 + 2]; o.w = acc[i][jj * 4 + 3];
        if (flags & 1) { o.x = gelu_f(o.x); o.y = gelu_f(o.y); o.z = gelu_f(o.z); o.w = gelu_f(o.w); }
        size_t cidx = (size_t)row * ldc + col;
        if (resid) {
          float4 rv = *(const float4*)(resid + cidx);
          o.x += rv.x; o.y += rv.y; o.z += rv.z; o.w += rv.w;
        }
        if (flags & 2) {
          float4 cv = *(const float4*)(C + cidx);
          o.x += cv.x; o.y += cv.y; o.z += cv.z; o.w += cv.w;
        }
        *(float4*)(C + cidx) = o;
      }
    }
  }
}

// ---------------- causal flash attention, fp32, emits ctx as bf16 hi/lo pair -----------
// grid (S/32, B*H); 256 thr = 16 groups x 16 lanes; group handles 2 q rows;
// lane x owns dims x*8..x*8+7. LDS rows padded 128->132 to break the 4-way
// bank conflict on stride-8 reads (round-1: 1.36e8 SQ_LDS_BANK_CONFLICT).
#define LP 132
__global__ __launch_bounds__(256)
void attn_kernel(const float* __restrict__ Qb, const float* __restrict__ Kb,
                 const float* __restrict__ Vb,
                 unsigned short* __restrict__ Ch, unsigned short* __restrict__ Cl)
{
  const int bh = blockIdx.y;
  const int b = bh >> 4, h = bh & 15;
  const int q0 = blockIdx.x * 32;
  const int g = threadIdx.x >> 4;
  const int x = threadIdx.x & 15;
  const float scl = 0.08838834764831845f;   // 1/sqrt(128)
  const size_t base = (size_t)b * Sn * Dn + (size_t)h * 128;
  const float* Q = Qb + base;
  const float* K = Kb + base;
  const float* V = Vb + base;
  const int s0 = q0 + 2 * g, s1 = s0 + 1;

  float q0r[8], q1r[8], c0[8], c1[8];
  {
    float4 qa = *(const float4*)&Q[(size_t)s0 * Dn + x * 8];
    float4 qb = *(const float4*)&Q[(size_t)s0 * Dn + x * 8 + 4];
    float4 qc = *(const float4*)&Q[(size_t)s1 * Dn + x * 8];
    float4 qd = *(const float4*)&Q[(size_t)s1 * Dn + x * 8 + 4];
    q0r[0]=qa.x*scl; q0r[1]=qa.y*scl; q0r[2]=qa.z*scl; q0r[3]=qa.w*scl;
    q0r[4]=qb.x*scl; q0r[5]=qb.y*scl; q0r[6]=qb.z*scl; q0r[7]=qb.w*scl;
    q1r[0]=qc.x*scl; q1r[1]=qc.y*scl; q1r[2]=qc.z*scl; q1r[3]=qc.w*scl;
    q1r[4]=qd.x*scl; q1r[5]=qd.y*scl; q1r[6]=qd.z*scl; q1r[7]=qd.w*scl;
  }
#pragma unroll
  for (int i = 0; i < 8; ++i) { c0[i] = 0.f; c1[i] = 0.f; }
  float m0 = -1e30f, m1 = -1e30f, l0a = 0.f, l1a = 0.f;
  __shared__ float Ks[32][LP];
  __shared__ float Vs[32][LP];

  for (int j0 = 0; j0 < q0 + 32; j0 += 32) {
    for (int u = threadIdx.x; u < 1024; u += 256) {
      int r = u >> 5, c4 = (u & 31) << 2;
      *(float4*)&Ks[r][c4] = *(const float4*)&K[(size_t)(j0 + r) * Dn + c4];
      *(float4*)&Vs[r][c4] = *(const float4*)&V[(size_t)(j0 + r) * Dn + c4];
    }
    __syncthreads();
    float p0[32], p1[32];
    float mt0 = m0, mt1 = m1;
#pragma unroll
    for (int j = 0; j < 32; ++j) {
      float4 kv0 = *(const float4*)&Ks[j][x * 8];
      float4 kv1 = *(const float4*)&Ks[j][x * 8 + 4];
      float pa = q0r[0]*kv0.x + q0r[1]*kv0.y + q0r[2]*kv0.z + q0r[3]*kv0.w
               + q0r[4]*kv1.x + q0r[5]*kv1.y + q0r[6]*kv1.z + q0r[7]*kv1.w;
      float pb = q1r[0]*kv0.x + q1r[1]*kv0.y + q1r[2]*kv0.z + q1r[3]*kv0.w
               + q1r[4]*kv1.x + q1r[5]*kv1.y + q1r[6]*kv1.z + q1r[7]*kv1.w;
#pragma unroll
      for (int mm = 8; mm > 0; mm >>= 1) {
        pa += __shfl_xor(pa, mm, 16);
        pb += __shfl_xor(pb, mm, 16);
      }
      int jj = j0 + j;
      pa = (jj <= s0) ? pa : -1e30f;
      pb = (jj <= s1) ? pb : -1e30f;
      p0[j] = pa; p1[j] = pb;
      mt0 = fmaxf(mt0, pa); mt1 = fmaxf(mt1, pb);
    }
    float cor0 = __expf(m0 - mt0), cor1 = __expf(m1 - mt1);
    l0a *= cor0; l1a *= cor1;
#pragma unroll
    for (int i = 0; i < 8; ++i) { c0[i] *= cor0; c1[i] *= cor1; }
#pragma unroll
    for (int j = 0; j < 32; ++j) {
      float w0 = __expf(p0[j] - mt0);
      float w1 = __expf(p1[j] - mt1);
      l0a += w0; l1a += w1;
      float4 vv0 = *(const float4*)&Vs[j][x * 8];
      float4 vv1 = *(const float4*)&Vs[j][x * 8 + 4];
      c0[0] += w0*vv0.x; c0[1] += w0*vv0.y; c0[2] += w0*vv0.z; c0[3] += w0*vv0.w;
      c0[4] += w0*vv1.x; c0[5] += w0*vv1.y; c0[6] += w0*vv1.z; c0[7] += w0*vv1.w;
      c1[0] += w1*vv0.x; c1[1] += w1*vv0.y; c1[2] += w1*vv0.z; c1[3] += w1*vv0.w;
      c1[4] += w1*vv1.x; c1[5] += w1*vv1.y; c1[6] += w1*vv1.z; c1[7] += w1*vv1.w;
    }
    m0 = mt0; m1 = mt1;
    __syncthreads();
  }
  const float inv0 = 1.0f / l0a, inv1 = 1.0f / l1a;
  float o0[8], o1[8];
#pragma unroll
  for (int i = 0; i < 8; ++i) { o0[i] = c0[i] * inv0; o1[i] = c1[i] * inv1; }
  U8 hu, lu;
#pragma unroll
  for (int j = 0; j < 8; ++j) {
    hu.s[j] = f2bf(o0[j]);
    lu.s[j] = f2bf(o0[j] - bf2f(hu.s[j]));
  }
  *(uint4*)&Ch[base + (size_t)s0 * Dn + x * 8] = hu.v;
  *(uint4*)&Cl[base + (size_t)s0 * Dn + x * 8] = lu.v;
#pragma unroll
  for (int j = 0; j < 8; ++j) {
    hu.s[j] = f2bf(o1[j]);
    lu.s[j] = f2bf(o1[j] - bf2f(hu.s[j]));
  }
  *(uint4*)&Ch[base + (size_t)s1 * Dn + x * 8] = hu.v;
  *(uint4*)&Cl[base + (size_t)s1 * Dn + x * 8] = lu.v;
}

// ---------------- final per-token routing fixup (out2 already in d_out) ----------------
__global__ __launch_bounds__(256)
void select_kernel(const float* __restrict__ h, const float* __restrict__ bias,
                   const float* __restrict__ out1,
                   const int* __restrict__ dec, float* __restrict__ out)
{
  int i = blockIdx.x * 256 + threadIdx.x;
  if (i >= Tn * Dn / 4) return;
  int t = i >> 9;
  int de = dec[t];
  if (de == 2) return;                         // out2 already resident in d_out
  int d4 = (i & 511) << 2;
  size_t idx = (size_t)t * Dn + d4;
  float4 o;
  if (de == 0) {
    float4 hv = *(const float4*)(h + idx);
    float4 bv = *(const float4*)(bias + d4);
    o.x = hv.x + bv.x; o.y = hv.y + bv.y; o.z = hv.z + bv.z; o.w = hv.w + bv.w;
  } else {
    o = *(const float4*)(out1 + idx);
  }
  *(float4*)(out + idx) = o;
}

extern "C" void kernel_launch(void* const* d_in, const int* in_sizes, int n_in,
                              void* d_out, int out_size, void* d_ws, size_t ws_size,
                              hipStream_t stream) {
  const float* hid    = (const float*)d_in[0];
  const float* sbias  = (const float*)d_in[1];
  const float* w_down = (const float*)d_in[2];
  const float* w_up   = (const float*)d_in[3];
  const float* w_rout = (const float*)d_in[4];
  const float* ln1s   = (const float*)d_in[5];
  const float* ln1b   = (const float*)d_in[6];
  const float* wq     = (const float*)d_in[7];
  const float* wk     = (const float*)d_in[8];
  const float* wv     = (const float*)d_in[9];
  const float* wo     = (const float*)d_in[10];
  const float* ln2s   = (const float*)d_in[11];
  const float* ln2b   = (const float*)d_in[12];
  const float* w_ff1  = (const float*)d_in[13];
  const float* w_ff2  = (const float*)d_in[14];

  const size_t TD  = (size_t)Tn * Dn;                // 8M elements
  const size_t WEL = (size_t)Dn * FC;                // 4M elements (weight chunk)

  // ---- workspace plan (aliased by liveness; total ~144.5 MB) ----
  char* p = (char*)d_ws;
  auto alloc = [&](size_t bytes) -> char* {
    char* r = p; p += (bytes + 255) & ~(size_t)255; return r;
  };
  float* FA = (float*)alloc(TD * 4);                 // Q (steps 2-3) -> x2 (steps 4-6)
  char*  BB = alloc(TD * 4);                         // K (steps 2-3) -> gelu pair (step 6)
  float* FC3 = (float*)alloc(TD * 4);                // V (steps 2-3) -> out1 (steps 7-8)
  unsigned short* P1h = (unsigned short*)alloc(TD * 2);  // xn -> ctx -> xn2 (hi)
  unsigned short* P1l = (unsigned short*)alloc(TD * 2);  // xn -> ctx -> xn2 (lo)
  unsigned short* Wh  = (unsigned short*)alloc(WEL * 2); // weight pair scratch
  unsigned short* Wl  = (unsigned short*)alloc(WEL * 2);
  float* hd = (float*)alloc((size_t)Tn * Rn * 4);
  int* dec  = (int*)alloc((size_t)Tn * 4);
  if ((size_t)(p - (char*)d_ws) > ws_size) return;   // insufficient scratch: loud fail

  float* Qb = FA;
  float* Kb = (float*)BB;
  float* Vb = FC3;
  float* x2 = FA;                                    // after attn, Q dead
  unsigned short* Gh = (unsigned short*)BB;          // after attn, K dead
  unsigned short* Gl = Gh + TD;
  float* out1 = FC3;                                 // after attn, V dead
  float* out2 = (float*)d_out;                       // accumulate FFN directly in d_out

  const int cw = (int)(WEL / 8 / 256);               // 2048 blocks for weight cvt
  dim3 gq(Dn / BN, Tn / BM);                         // (16, 32)

  // 1. LN1 + router (router reads RAW hidden)
  ln_router_kernel<<<Tn, 256, 0, stream>>>(hid, ln1s, ln1b, w_rout, P1h, P1l, dec);
  // 2. Q,K,V = xn @ w{q,k,v}.T   (split-bf16 MFMA)
  cvt_pair_kernel<<<cw, 256, 0, stream>>>(wq, Dn, Dn, Wh, Wl, (int)(WEL / 8));
  gemm_bf16s<<<gq, 256, 0, stream>>>(P1h, P1l, Wh, Wl, Dn, Qb, nullptr, nullptr, nullptr, Dn, 0);
  cvt_pair_kernel<<<cw, 256, 0, stream>>>(wk, Dn, Dn, Wh, Wl, (int)(WEL / 8));
  gemm_bf16s<<<gq, 256, 0, stream>>>(P1h, P1l, Wh, Wl, Dn, Kb, nullptr, nullptr, nullptr, Dn, 0);
  cvt_pair_kernel<<<cw, 256, 0, stream>>>(wv, Dn, Dn, Wh, Wl, (int)(WEL / 8));
  gemm_bf16s<<<gq, 256, 0, stream>>>(P1h, P1l, Wh, Wl, Dn, Vb, nullptr, nullptr, nullptr, Dn, 0);
  // 3. attention -> ctx pair (into P1; xn dead)
  attn_kernel<<<dim3(Sn / 32, 2 * Hn), 256, 0, stream>>>(Qb, Kb, Vb, P1h, P1l);
  // 4. x2 = hid + ctx @ wo.T   (into FA; Q dead)
  cvt_pair_kernel<<<cw, 256, 0, stream>>>(wo, Dn, Dn, Wh, Wl, (int)(WEL / 8));
  gemm_bf16s<<<gq, 256, 0, stream>>>(P1h, P1l, Wh, Wl, Dn, x2, hid, nullptr, nullptr, Dn, 0);
  // 5. xn2 = LN2(x2) -> P1 pair (ctx pair consumed)
  ln_router_kernel<<<Tn, 256, 0, stream>>>(x2, ln2s, ln2b, nullptr, P1h, P1l, nullptr);
  // 6. FFN chunked over F: out2 (d_out) = x2 + gelu(xn2 @ ff1.T) @ ff2.T
  for (int f0 = 0; f0 < Fn; f0 += FC) {
    cvt_pair_kernel<<<cw, 256, 0, stream>>>(w_ff1 + (size_t)f0 * Dn, Dn, Dn, Wh, Wl, (int)(WEL / 8));
    gemm_bf16s<<<gq, 256, 0, stream>>>(P1h, P1l, Wh, Wl, Dn, nullptr, nullptr, Gh, Gl, FC, 1);
    cvt_pair_kernel<<<cw, 256, 0, stream>>>(w_ff2 + f0, Fn, FC, Wh, Wl, (int)(WEL / 8));
    gemm_bf16s<<<gq, 256, 0, stream>>>(Gh, Gl, Wh, Wl, FC, out2,
                                       (f0 == 0) ? x2 : nullptr, nullptr, nullptr, Dn,
                                       (f0 == 0) ? 0 : 2);
  }
  // 7. adapter (fp32 vector GEMM; tiny): out1 = hid + (hid @ w_down.T) @ w_up.T
  gemm_nt<<<dim3(1, Tn / GBM), 256, 0, stream>>>(hid, Dn, w_down, Dn, hd, Rn, nullptr, Tn, Rn, Dn, 0);
  gemm_nt<<<dim3(Dn / GBN, Tn / GBM), 256, 0, stream>>>(hd, Rn, w_up, Rn, out1, Dn, hid, Tn, Dn, Rn, 0);
  // 8. routing fixup (path-2 rows already in d_out)
  int nv4 = Tn * Dn / 4;
  select_kernel<<<(nv4 + 255) / 256, 256, 0, stream>>>(hid, sbias, out1, dec, (float*)d_out);
}

// Round 8
// 2852.245 us; speedup vs baseline: 2.8798x; 1.4025x over previous
//
#include <hip/hip_runtime.h>
#include <math.h>

#define Tn 4096   // B*S tokens
#define Dn 2048   // hidden
#define Sn 2048   // seq
#define Hn 16     // heads
#define Fn 8192   // ffn
#define Rn 32     // adapter rank
#define FC 2048   // ffn chunk size

typedef short bf16x8 __attribute__((ext_vector_type(8)));
typedef float f32x4 __attribute__((ext_vector_type(4)));

union U8 { unsigned short s[8]; uint4 v; };

__device__ __forceinline__ float gelu_f(float x) {
  return 0.5f * x * (1.0f + tanhf(0.7978845608028654f * (x + 0.044715f * x * x * x)));
}

__device__ __forceinline__ unsigned short f2bf(float x) {   // RNE
  union { float f; unsigned u; } v; v.f = x;
  unsigned r = v.u + 0x7FFFu + ((v.u >> 16) & 1u);
  return (unsigned short)(r >> 16);
}
__device__ __forceinline__ float bf2f(unsigned short h) {
  union { unsigned u; float f; } v; v.u = ((unsigned)h) << 16; return v.f;
}

__device__ __forceinline__ void glds16(const unsigned short* g, unsigned short* lds) {
  __builtin_amdgcn_global_load_lds((const __attribute__((address_space(1))) void*)g,
                                   (__attribute__((address_space(3))) void*)lds, 16, 0, 0);
}

// ---------------- fused LayerNorm (+ optional router argmax), bf16 hi/lo output --------
__global__ __launch_bounds__(256)
void ln_router_kernel(const float* __restrict__ x,
                      const float* __restrict__ sc,
                      const float* __restrict__ bi,
                      const float* __restrict__ wr,
                      unsigned short* __restrict__ xh,
                      unsigned short* __restrict__ xl,
                      int* __restrict__ dec)
{
  const int t = blockIdx.x;
  const int tid = threadIdx.x;
  const float* row = x + (size_t)t * Dn;
  const int d0 = tid * 8;
  float4 v0 = *(const float4*)(row + d0);
  float4 v1 = *(const float4*)(row + d0 + 4);
  float a[5];
  a[0] = v0.x + v0.y + v0.z + v0.w + v1.x + v1.y + v1.z + v1.w;
  a[1] = v0.x*v0.x + v0.y*v0.y + v0.z*v0.z + v0.w*v0.w
       + v1.x*v1.x + v1.y*v1.y + v1.z*v1.z + v1.w*v1.w;
  a[2] = 0.f; a[3] = 0.f; a[4] = 0.f;
  if (wr) {
#pragma unroll
    for (int r = 0; r < 3; ++r) {
      float4 w0 = *(const float4*)(wr + r * Dn + d0);
      float4 w1 = *(const float4*)(wr + r * Dn + d0 + 4);
      a[2 + r] = v0.x*w0.x + v0.y*w0.y + v0.z*w0.z + v0.w*w0.w
               + v1.x*w1.x + v1.y*w1.y + v1.z*w1.z + v1.w*w1.w;
    }
  }
#pragma unroll
  for (int i = 0; i < 5; ++i) {
#pragma unroll
    for (int off = 32; off > 0; off >>= 1)
      a[i] += __shfl_down(a[i], off);
  }
  __shared__ float red[4][5];
  __shared__ float fin[5];
  const int wv = tid >> 6, ln = tid & 63;
  if (ln == 0) {
#pragma unroll
    for (int i = 0; i < 5; ++i) red[wv][i] = a[i];
  }
  __syncthreads();
  if (tid == 0) {
#pragma unroll
    for (int i = 0; i < 5; ++i)
      fin[i] = red[0][i] + red[1][i] + red[2][i] + red[3][i];
    if (dec) {
      float l0 = fin[2], l1 = fin[3], l2 = fin[4];
      int best = 0; float bl = l0;
      if (l1 > bl) { best = 1; bl = l1; }
      if (l2 > bl) { best = 2; }
      dec[t] = best;
    }
  }
  __syncthreads();
  const float mu  = fin[0] * (1.0f / Dn);
  const float var = fin[1] * (1.0f / Dn) - mu * mu;
  const float rs  = rsqrtf(var + 1e-5f);
  float4 s0 = *(const float4*)(sc + d0);
  float4 s1 = *(const float4*)(sc + d0 + 4);
  float4 b0 = *(const float4*)(bi + d0);
  float4 b1 = *(const float4*)(bi + d0 + 4);
  float o[8];
  o[0] = (v0.x - mu) * rs * s0.x + b0.x;
  o[1] = (v0.y - mu) * rs * s0.y + b0.y;
  o[2] = (v0.z - mu) * rs * s0.z + b0.z;
  o[3] = (v0.w - mu) * rs * s0.w + b0.w;
  o[4] = (v1.x - mu) * rs * s1.x + b1.x;
  o[5] = (v1.y - mu) * rs * s1.y + b1.y;
  o[6] = (v1.z - mu) * rs * s1.z + b1.z;
  o[7] = (v1.w - mu) * rs * s1.w + b1.w;
  U8 hu, lu;
#pragma unroll
  for (int j = 0; j < 8; ++j) {
    hu.s[j] = f2bf(o[j]);
    lu.s[j] = f2bf(o[j] - bf2f(hu.s[j]));
  }
  *(uint4*)&xh[(size_t)t * Dn + d0] = hu.v;
  *(uint4*)&xl[(size_t)t * Dn + d0] = lu.v;
}

// ---------------- fp32 -> bf16 hi/lo pair (weights) ----------------
__global__ __launch_bounds__(256)
void cvt_pair_kernel(const float* __restrict__ src, int ld, int K,
                     unsigned short* __restrict__ H, unsigned short* __restrict__ L,
                     int total8)
{
  int i = blockIdx.x * 256 + threadIdx.x;
  if (i >= total8) return;
  size_t e = (size_t)i * 8;
  int row = (int)(e / (size_t)K);
  int col = (int)(e % (size_t)K);
  const float* s = src + (size_t)row * ld + col;
  float4 v0 = *(const float4*)s;
  float4 v1 = *(const float4*)(s + 4);
  float o[8] = {v0.x, v0.y, v0.z, v0.w, v1.x, v1.y, v1.z, v1.w};
  U8 hu, lu;
#pragma unroll
  for (int j = 0; j < 8; ++j) {
    hu.s[j] = f2bf(o[j]);
    lu.s[j] = f2bf(o[j] - bf2f(hu.s[j]));
  }
  *(uint4*)&H[e] = hu.v;
  *(uint4*)&L[e] = lu.v;
}

// ---------------- split-bf16 MFMA GEMM: C = (Ah+Al)[M,K] @ (Bh+Bl)[N,K]^T ----------------
// mode bits: 1=gelu+pair-out, 4=plain pair-out, 2=fp32 accumulate, 0=fp32 (+resid)
#define BM 128
#define BN 128
#define BK 32
__global__ __launch_bounds__(256)
void gemm_bf16s(const unsigned short* __restrict__ Ah, const unsigned short* __restrict__ Al,
                const unsigned short* __restrict__ Bh, const unsigned short* __restrict__ Bl,
                int K, float* __restrict__ C, const float* __restrict__ resid,
                unsigned short* __restrict__ Gh, unsigned short* __restrict__ Gl,
                int N, int mode)
{
  __shared__ unsigned short sAh[BM * BK];
  __shared__ unsigned short sAl[BM * BK];
  __shared__ unsigned short sBh[BN * BK];
  __shared__ unsigned short sBl[BN * BK];
  const int tid = threadIdx.x;
  const int l = tid & 63, w = tid >> 6;
  const int wm = w >> 1, wn = w & 1;
  const int fr = l & 15, kg = (l >> 4) * 8;
  const int bm = blockIdx.y * BM, bn = blockIdx.x * BN;

  f32x4 acc[4][4];
#pragma unroll
  for (int m = 0; m < 4; ++m)
#pragma unroll
    for (int n = 0; n < 4; ++n)
#pragma unroll
      for (int q = 0; q < 4; ++q) acc[m][n][q] = 0.f;

  for (int k0 = 0; k0 < K; k0 += BK) {
#pragma unroll
    for (int r = 0; r < 2; ++r) {
      const int c = r * 256 + tid;
      const int row = c >> 2, q = c & 3;
      const size_t ga = (size_t)(bm + row) * K + k0 + q * 8;
      const size_t gb = (size_t)(bn + row) * K + k0 + q * 8;
      const int ub = (r * 256 + w * 64) * 8;
      glds16(Ah + ga, sAh + ub);
      glds16(Al + ga, sAl + ub);
      glds16(Bh + gb, sBh + ub);
      glds16(Bl + gb, sBl + ub);
    }
    __syncthreads();

    bf16x8 ah[4], al[4], bh[4], bl[4];
#pragma unroll
    for (int m = 0; m < 4; ++m) {
      const int ro = (wm * 64 + m * 16 + fr) * BK + kg;
      ah[m] = *(const bf16x8*)&sAh[ro];
      al[m] = *(const bf16x8*)&sAl[ro];
    }
#pragma unroll
    for (int n = 0; n < 4; ++n) {
      const int ro = (wn * 64 + n * 16 + fr) * BK + kg;
      bh[n] = *(const bf16x8*)&sBh[ro];
      bl[n] = *(const bf16x8*)&sBl[ro];
    }
#pragma unroll
    for (int m = 0; m < 4; ++m)
#pragma unroll
      for (int n = 0; n < 4; ++n) {
        acc[m][n] = __builtin_amdgcn_mfma_f32_16x16x32_bf16(ah[m], bh[n], acc[m][n], 0, 0, 0);
        acc[m][n] = __builtin_amdgcn_mfma_f32_16x16x32_bf16(ah[m], bl[n], acc[m][n], 0, 0, 0);
        acc[m][n] = __builtin_amdgcn_mfma_f32_16x16x32_bf16(al[m], bh[n], acc[m][n], 0, 0, 0);
      }
    __syncthreads();
  }

  const int rbase = (l >> 4) * 4;
#pragma unroll
  for (int m = 0; m < 4; ++m) {
#pragma unroll
    for (int i = 0; i < 4; ++i) {
      const int row = bm + wm * 64 + m * 16 + rbase + i;
#pragma unroll
      for (int n = 0; n < 4; ++n) {
        const int col = bn + wn * 64 + n * 16 + fr;
        float v = acc[m][n][i];
        const size_t idx = (size_t)row * N + col;
        if (mode & 5) {               // pair output (1 => gelu first)
          float g = (mode & 1) ? gelu_f(v) : v;
          unsigned short h = f2bf(g);
          Gh[idx] = h;
          Gl[idx] = f2bf(g - bf2f(h));
        } else {
          if (resid) v += resid[idx];
          if (mode & 2) v += C[idx];
          C[idx] = v;
        }
      }
    }
  }
}

// ---------------- fp32 vector GEMM (adapter only) ----------------
#define GBM 128
#define GBN 128
#define GBK 16
__global__ __launch_bounds__(256)
void gemm_nt(const float* __restrict__ A, int lda,
             const float* __restrict__ B, int ldb,
             float* __restrict__ C, int ldc,
             const float* __restrict__ resid,
             int M, int N, int K, int flags)
{
  __shared__ float As[GBK][GBM + 4];
  __shared__ float Bs[GBK][GBN + 4];
  const int bm = blockIdx.y * GBM;
  const int bn = blockIdx.x * GBN;
  const int tid = threadIdx.x;
  const int ty = tid >> 4, tx = tid & 15;
  float acc[8][8];
#pragma unroll
  for (int i = 0; i < 8; ++i)
#pragma unroll
    for (int j = 0; j < 8; ++j) acc[i][j] = 0.f;

  for (int k0 = 0; k0 < K; k0 += GBK) {
#pragma unroll
    for (int i = 0; i < 2; ++i) {
      int fid = tid + i * 256;
      int row = fid >> 2, c = (fid & 3) << 2;
      float4 av = *(const float4*)(A + (size_t)(bm + row) * lda + k0 + c);
      As[c + 0][row] = av.x; As[c + 1][row] = av.y;
      As[c + 2][row] = av.z; As[c + 3][row] = av.w;
      float4 bv = make_float4(0.f, 0.f, 0.f, 0.f);
      if (bn + row < N)
        bv = *(const float4*)(B + (size_t)(bn + row) * ldb + k0 + c);
      Bs[c + 0][row] = bv.x; Bs[c + 1][row] = bv.y;
      Bs[c + 2][row] = bv.z; Bs[c + 3][row] = bv.w;
    }
    __syncthreads();
#pragma unroll
    for (int k = 0; k < GBK; ++k) {
      float4 a0 = *(const float4*)&As[k][ty * 4];
      float4 a1 = *(const float4*)&As[k][64 + ty * 4];
      float4 b0 = *(const float4*)&Bs[k][tx * 4];
      float4 b1 = *(const float4*)&Bs[k][64 + tx * 4];
      float aa[8] = {a0.x, a0.y, a0.z, a0.w, a1.x, a1.y, a1.z, a1.w};
      float bb[8] = {b0.x, b0.y, b0.z, b0.w, b1.x, b1.y, b1.z, b1.w};
#pragma unroll
      for (int i = 0; i < 8; ++i)
#pragma unroll
        for (int j = 0; j < 8; ++j)
          acc[i][j] += aa[i] * bb[j];
    }
    __syncthreads();
  }
#pragma unroll
  for (int i = 0; i < 8; ++i) {
    int row = bm + ((i < 4) ? (ty * 4 + i) : (64 + ty * 4 + i - 4));
#pragma unroll
    for (int jj = 0; jj < 2; ++jj) {
      int col = bn + ((jj == 0) ? (tx * 4) : (64 + tx * 4));
      if (col < N) {
        float4 o;
        o.x = acc[i][jj * 4 + 0]; o.y = acc[i][jj * 4 + 1];
        o.z = acc[i][jj * 4 + 2]; o.w = acc[i][jj * 4 + 3];
        if (flags & 1) { o.x = gelu_f(o.x); o.y = gelu_f(o.y); o.z = gelu_f(o.z); o.w = gelu_f(o.w); }
        size_t cidx = (size_t)row * ldc + col;
        if (resid) {
          float4 rv = *(const float4*)(resid + cidx);
          o.x += rv.x; o.y += rv.y; o.z += rv.z; o.w += rv.w;
        }
        if (flags & 2) {
          float4 cv = *(const float4*)(C + cidx);
          o.x += cv.x; o.y += cv.y; o.z += cv.z; o.w += cv.w;
        }
        *(float4*)(C + cidx) = o;
      }
    }
  }
}

// ---------------- per-head V transpose: [B,S,H*128] pair -> [B*H,128,S] pair ----------
__global__ __launch_bounds__(256)
void vtrans_kernel(const unsigned short* __restrict__ Vh, const unsigned short* __restrict__ Vl,
                   unsigned short* __restrict__ Th, unsigned short* __restrict__ Tl)
{
  __shared__ unsigned short T[64][68];
  const int j0 = blockIdx.x * 64;
  const int d0 = blockIdx.y * 64;
  const int bh = blockIdx.z;
  const int b = bh >> 4, h = bh & 15;
  const int tid = threadIdx.x;
  const int jr = tid >> 2, cc = (tid & 3) * 16;   // load: row j0+jr, cols d0+cc..+15
  const size_t inrow = ((size_t)b * Sn + j0 + jr) * Dn + h * 128 + d0 + cc;
  const int dr = tid >> 2, jc = (tid & 3) * 16;   // store: row d0+dr, cols j0+jc..+15
  const size_t outrow = ((size_t)bh * 128 + d0 + dr) * (size_t)Sn + j0 + jc;
#pragma unroll
  for (int pass = 0; pass < 2; ++pass) {
    const unsigned short* src = pass ? Vl : Vh;
    unsigned short* dst = pass ? Tl : Th;
    ushort4 u[4];
#pragma unroll
    for (int c = 0; c < 4; ++c) u[c] = *(const ushort4*)&src[inrow + c * 4];
    if (pass) __syncthreads();                    // pass-0 reads done before overwrite
#pragma unroll
    for (int c = 0; c < 4; ++c) {
      T[cc + c*4 + 0][jr] = u[c].x;
      T[cc + c*4 + 1][jr] = u[c].y;
      T[cc + c*4 + 2][jr] = u[c].z;
      T[cc + c*4 + 3][jr] = u[c].w;
    }
    __syncthreads();
#pragma unroll
    for (int c = 0; c < 4; ++c)
      *(ushort4*)&dst[outrow + c * 4] = *(const ushort4*)&T[dr][jc + c * 4];
  }
}

// ---------------- MFMA causal flash attention (split-bf16) ----------------
// grid (Sn/64, B*Hn), 256 thr = 4 waves; wave w owns q rows q0+w*16..+15.
// Fragment conventions identical to gemm_bf16s (HW-validated round 4):
//   A-frag: lane holds A[row=l&15][k=(l>>4)*8+i];  B-frag: B[col=l&15][k=(l>>4)*8+i]
//   D: row=(l>>4)*4+i (A side), col=l&15 (B side)
__global__ __launch_bounds__(256)
void attn_mfma(const unsigned short* __restrict__ Qh, const unsigned short* __restrict__ Ql,
               const unsigned short* __restrict__ Kh, const unsigned short* __restrict__ Kl,
               const unsigned short* __restrict__ Vth, const unsigned short* __restrict__ Vtl,
               unsigned short* __restrict__ Ch, unsigned short* __restrict__ Cl)
{
  const int bh = blockIdx.y;
  const int b = bh >> 4, h = bh & 15;
  const int q0 = blockIdx.x * 64;
  const int tid = threadIdx.x;
  const int w = tid >> 6, l = tid & 63;
  const int lr = l & 15, lg = l >> 4;
  const int q0w = q0 + w * 16;
  const float scl = 0.08838834764831845f;   // 1/sqrt(128)

  // Q A-fragments (row = q0w+lr), 128 dims = 4 k-steps, hi+lo
  const size_t qrow = ((size_t)b * Sn + q0w + lr) * (size_t)Dn + h * 128;
  bf16x8 qfh[4], qfl[4];
#pragma unroll
  for (int ks = 0; ks < 4; ++ks) {
    qfh[ks] = *(const bf16x8*)&Qh[qrow + ks * 32 + lg * 8];
    qfl[ks] = *(const bf16x8*)&Ql[qrow + ks * 32 + lg * 8];
  }

  f32x4 cacc[8];                       // cacc[dt][i] = ctx[q=q0w+lg*4+i][d=dt*16+lr]
#pragma unroll
  for (int dt = 0; dt < 8; ++dt)
#pragma unroll
    for (int i = 0; i < 4; ++i) cacc[dt][i] = 0.f;
  float mrun[4], lrun[4];
#pragma unroll
  for (int i = 0; i < 4; ++i) { mrun[i] = -1e30f; lrun[i] = 0.f; }

  __shared__ unsigned short PhB[4][512];   // wave-private P hi [16q][32j]
  __shared__ unsigned short PlB[4][512];
  unsigned short* ph = PhB[w];
  unsigned short* pl = PlB[w];

  const size_t krowbase = (size_t)b * Sn * Dn + h * 128;
  const size_t vtbase = (size_t)bh * 128 * (size_t)Sn;
  const int ntw = (q0w + 15) / 32 + 1;     // tiles with j0 <= q0w+15

  for (int t = 0; t < ntw; ++t) {
    const int j0 = t * 32;
    // ---- scores: S[16q][32j], 3-pass split, 24 mfma ----
    f32x4 s0 = {0.f, 0.f, 0.f, 0.f}, s1 = {0.f, 0.f, 0.f, 0.f};
    const size_t kr0 = krowbase + (size_t)(j0 + lr) * Dn;
    const size_t kr1 = krowbase + (size_t)(j0 + 16 + lr) * Dn;
#pragma unroll
    for (int ks = 0; ks < 4; ++ks) {
      bf16x8 kh0 = *(const bf16x8*)&Kh[kr0 + ks * 32 + lg * 8];
      bf16x8 kl0 = *(const bf16x8*)&Kl[kr0 + ks * 32 + lg * 8];
      s0 = __builtin_amdgcn_mfma_f32_16x16x32_bf16(qfh[ks], kh0, s0, 0, 0, 0);
      s0 = __builtin_amdgcn_mfma_f32_16x16x32_bf16(qfl[ks], kh0, s0, 0, 0, 0);
      s0 = __builtin_amdgcn_mfma_f32_16x16x32_bf16(qfh[ks], kl0, s0, 0, 0, 0);
      bf16x8 kh1 = *(const bf16x8*)&Kh[kr1 + ks * 32 + lg * 8];
      bf16x8 kl1 = *(const bf16x8*)&Kl[kr1 + ks * 32 + lg * 8];
      s1 = __builtin_amdgcn_mfma_f32_16x16x32_bf16(qfh[ks], kh1, s1, 0, 0, 0);
      s1 = __builtin_amdgcn_mfma_f32_16x16x32_bf16(qfl[ks], kh1, s1, 0, 0, 0);
      s1 = __builtin_amdgcn_mfma_f32_16x16x32_bf16(qfh[ks], kl1, s1, 0, 0, 0);
    }
    // ---- online softmax (per lane: 4 q-rows, j = j0+{lr, 16+lr}) ----
    float p0a[4], p1a[4], cor[4];
#pragma unroll
    for (int i = 0; i < 4; ++i) {
      const int qg = q0w + lg * 4 + i;
      float a0 = s0[i] * scl; if (j0 + lr > qg) a0 = -1e30f;
      float a1 = s1[i] * scl; if (j0 + 16 + lr > qg) a1 = -1e30f;
      float mx = fmaxf(a0, a1);
      mx = fmaxf(mx, __shfl_xor(mx, 1));
      mx = fmaxf(mx, __shfl_xor(mx, 2));
      mx = fmaxf(mx, __shfl_xor(mx, 4));
      mx = fmaxf(mx, __shfl_xor(mx, 8));
      const float mt = fmaxf(mrun[i], mx);
      cor[i] = __expf(mrun[i] - mt);
      mrun[i] = mt;
      float p0 = __expf(a0 - mt);
      float p1 = __expf(a1 - mt);
      p0a[i] = p0; p1a[i] = p1;
      float ls = p0 + p1;
      ls += __shfl_xor(ls, 1);
      ls += __shfl_xor(ls, 2);
      ls += __shfl_xor(ls, 4);
      ls += __shfl_xor(ls, 8);
      lrun[i] = lrun[i] * cor[i] + ls;
    }
    // ---- P -> bf16 pair via wave-private LDS (layout transpose to A-frag) ----
#pragma unroll
    for (int i = 0; i < 4; ++i) {
      const int qrl = (lg * 4 + i) * 32;
      unsigned short h0 = f2bf(p0a[i]);
      ph[qrl + lr] = h0;
      pl[qrl + lr] = f2bf(p0a[i] - bf2f(h0));
      unsigned short h1 = f2bf(p1a[i]);
      ph[qrl + 16 + lr] = h1;
      pl[qrl + 16 + lr] = f2bf(p1a[i] - bf2f(h1));
    }
    // ---- rescale ctx ----
#pragma unroll
    for (int dt = 0; dt < 8; ++dt)
#pragma unroll
      for (int i = 0; i < 4; ++i) cacc[dt][i] *= cor[i];
    // ---- PV: 3-pass split, 24 mfma; A=P (from LDS), B=V^T rows (global) ----
    bf16x8 pah = *(const bf16x8*)&ph[lr * 32 + lg * 8];
    bf16x8 pal = *(const bf16x8*)&pl[lr * 32 + lg * 8];
#pragma unroll
    for (int dt = 0; dt < 8; ++dt) {
      const size_t vrow = vtbase + (size_t)(dt * 16 + lr) * Sn + j0 + lg * 8;
      bf16x8 vh = *(const bf16x8*)&Vth[vrow];
      bf16x8 vl = *(const bf16x8*)&Vtl[vrow];
      cacc[dt] = __builtin_amdgcn_mfma_f32_16x16x32_bf16(pah, vh, cacc[dt], 0, 0, 0);
      cacc[dt] = __builtin_amdgcn_mfma_f32_16x16x32_bf16(pah, vl, cacc[dt], 0, 0, 0);
      cacc[dt] = __builtin_amdgcn_mfma_f32_16x16x32_bf16(pal, vh, cacc[dt], 0, 0, 0);
    }
  }
  // ---- epilogue: normalize, split, store ctx pair ----
#pragma unroll
  for (int i = 0; i < 4; ++i) {
    const float inv = 1.0f / lrun[i];
    const size_t obase = ((size_t)b * Sn + q0w + lg * 4 + i) * Dn + h * 128 + lr;
#pragma unroll
    for (int dt = 0; dt < 8; ++dt) {
      float v = cacc[dt][i] * inv;
      unsigned short hh = f2bf(v);
      Ch[obase + dt * 16] = hh;
      Cl[obase + dt * 16] = f2bf(v - bf2f(hh));
    }
  }
}

// ---------------- final per-token routing fixup (out2 already in d_out) ----------------
__global__ __launch_bounds__(256)
void select_kernel(const float* __restrict__ h, const float* __restrict__ bias,
                   const float* __restrict__ out1,
                   const int* __restrict__ dec, float* __restrict__ out)
{
  int i = blockIdx.x * 256 + threadIdx.x;
  if (i >= Tn * Dn / 4) return;
  int t = i >> 9;
  int de = dec[t];
  if (de == 2) return;
  int d4 = (i & 511) << 2;
  size_t idx = (size_t)t * Dn + d4;
  float4 o;
  if (de == 0) {
    float4 hv = *(const float4*)(h + idx);
    float4 bv = *(const float4*)(bias + d4);
    o.x = hv.x + bv.x; o.y = hv.y + bv.y; o.z = hv.z + bv.z; o.w = hv.w + bv.w;
  } else {
    o = *(const float4*)(out1 + idx);
  }
  *(float4*)(out + idx) = o;
}

extern "C" void kernel_launch(void* const* d_in, const int* in_sizes, int n_in,
                              void* d_out, int out_size, void* d_ws, size_t ws_size,
                              hipStream_t stream) {
  const float* hid    = (const float*)d_in[0];
  const float* sbias  = (const float*)d_in[1];
  const float* w_down = (const float*)d_in[2];
  const float* w_up   = (const float*)d_in[3];
  const float* w_rout = (const float*)d_in[4];
  const float* ln1s   = (const float*)d_in[5];
  const float* ln1b   = (const float*)d_in[6];
  const float* wq     = (const float*)d_in[7];
  const float* wk     = (const float*)d_in[8];
  const float* wv     = (const float*)d_in[9];
  const float* wo     = (const float*)d_in[10];
  const float* ln2s   = (const float*)d_in[11];
  const float* ln2b   = (const float*)d_in[12];
  const float* w_ff1  = (const float*)d_in[13];
  const float* w_ff2  = (const float*)d_in[14];

  const size_t TD  = (size_t)Tn * Dn;           // 8M elems
  const size_t WEL = (size_t)Dn * FC;           // 4M elems

  // ---- workspace (aliased by liveness; ~144.6 MB) ----
  char* p = (char*)d_ws;
  auto alloc = [&](size_t bytes) -> char* {
    char* r = p; p += (bytes + 255) & ~(size_t)255; return r;
  };
  unsigned short* P1h = (unsigned short*)alloc(TD * 2);  // xn -> ctx -> xn2 (hi)
  unsigned short* P1l = (unsigned short*)alloc(TD * 2);
  unsigned short* B2  = (unsigned short*)alloc(TD * 2);  // Vh -> Qh -> x2(half)
  unsigned short* B3  = (unsigned short*)alloc(TD * 2);  // Vl -> Ql -> x2(half)
  unsigned short* B4  = (unsigned short*)alloc(TD * 2);  // Kh -> gelu hi
  unsigned short* B5  = (unsigned short*)alloc(TD * 2);  // Kl -> gelu lo
  unsigned short* B6  = (unsigned short*)alloc(TD * 2);  // Vth -> out1(half)
  unsigned short* B7  = (unsigned short*)alloc(TD * 2);  // Vtl -> out1(half)
  unsigned short* Wh  = (unsigned short*)alloc(WEL * 2);
  unsigned short* Wl  = (unsigned short*)alloc(WEL * 2);
  float* hd = (float*)alloc((size_t)Tn * Rn * 4);
  int* dec  = (int*)alloc((size_t)Tn * 4);
  if ((size_t)(p - (char*)d_ws) > ws_size) return;

  unsigned short *Vh = B2, *Vl = B3;            // pre-transpose V pair
  unsigned short *Qh = B2, *Ql = B3;            // after vtrans
  unsigned short *Kh = B4, *Kl = B5;
  unsigned short *Vth = B6, *Vtl = B7;
  float* x2   = (float*)B2;                     // 32MB spans B2+B3 (Q dead after attn)
  unsigned short *Gh = B4, *Gl = B5;            // K dead after attn
  float* out1 = (float*)B6;                     // Vt dead after attn
  float* out2 = (float*)d_out;

  const int cw = (int)(WEL / 8 / 256);
  dim3 gq(Dn / BN, Tn / BM);

  // 1. LN1 + router
  ln_router_kernel<<<Tn, 256, 0, stream>>>(hid, ln1s, ln1b, w_rout, P1h, P1l, dec);
  // 2. V pair, then transpose per head
  cvt_pair_kernel<<<cw, 256, 0, stream>>>(wv, Dn, Dn, Wh, Wl, (int)(WEL / 8));
  gemm_bf16s<<<gq, 256, 0, stream>>>(P1h, P1l, Wh, Wl, Dn, nullptr, nullptr, Vh, Vl, Dn, 4);
  vtrans_kernel<<<dim3(Sn / 64, 2, 2 * Hn), 256, 0, stream>>>(Vh, Vl, Vth, Vtl);
  // 3. Q, K pairs (Q overwrites V region - V already transposed)
  cvt_pair_kernel<<<cw, 256, 0, stream>>>(wq, Dn, Dn, Wh, Wl, (int)(WEL / 8));
  gemm_bf16s<<<gq, 256, 0, stream>>>(P1h, P1l, Wh, Wl, Dn, nullptr, nullptr, Qh, Ql, Dn, 4);
  cvt_pair_kernel<<<cw, 256, 0, stream>>>(wk, Dn, Dn, Wh, Wl, (int)(WEL / 8));
  gemm_bf16s<<<gq, 256, 0, stream>>>(P1h, P1l, Wh, Wl, Dn, nullptr, nullptr, Kh, Kl, Dn, 4);
  // 4. MFMA attention -> ctx pair (xn dead)
  attn_mfma<<<dim3(Sn / 64, 2 * Hn), 256, 0, stream>>>(Qh, Ql, Kh, Kl, Vth, Vtl, P1h, P1l);
  // 5. x2 = hid + ctx @ wo.T (fp32, into Q region)
  cvt_pair_kernel<<<cw, 256, 0, stream>>>(wo, Dn, Dn, Wh, Wl, (int)(WEL / 8));
  gemm_bf16s<<<gq, 256, 0, stream>>>(P1h, P1l, Wh, Wl, Dn, x2, hid, nullptr, nullptr, Dn, 0);
  // 6. xn2 = LN2(x2) -> P1 pair
  ln_router_kernel<<<Tn, 256, 0, stream>>>(x2, ln2s, ln2b, nullptr, P1h, P1l, nullptr);
  // 7. FFN chunked: d_out = x2 + gelu(xn2 @ ff1.T) @ ff2.T
  for (int f0 = 0; f0 < Fn; f0 += FC) {
    cvt_pair_kernel<<<cw, 256, 0, stream>>>(w_ff1 + (size_t)f0 * Dn, Dn, Dn, Wh, Wl, (int)(WEL / 8));
    gemm_bf16s<<<gq, 256, 0, stream>>>(P1h, P1l, Wh, Wl, Dn, nullptr, nullptr, Gh, Gl, FC, 1);
    cvt_pair_kernel<<<cw, 256, 0, stream>>>(w_ff2 + f0, Fn, FC, Wh, Wl, (int)(WEL / 8));
    gemm_bf16s<<<gq, 256, 0, stream>>>(Gh, Gl, Wh, Wl, FC, out2,
                                       (f0 == 0) ? x2 : nullptr, nullptr, nullptr, Dn,
                                       (f0 == 0) ? 0 : 2);
  }
  // 8. adapter: out1 = hid + (hid @ w_down.T) @ w_up.T
  gemm_nt<<<dim3(1, Tn / GBM), 256, 0, stream>>>(hid, Dn, w_down, Dn, hd, Rn, nullptr, Tn, Rn, Dn, 0);
  gemm_nt<<<dim3(Dn / GBN, Tn / GBM), 256, 0, stream>>>(hd, Rn, w_up, Rn, out1, Dn, hid, Tn, Dn, Rn, 0);
  // 9. routing fixup
  int nv4 = Tn * Dn / 4;
  select_kernel<<<(nv4 + 255) / 256, 256, 0, stream>>>(hid, sbias, out1, dec, (float*)d_out);
}

// Round 11
// 2749.763 us; speedup vs baseline: 2.9871x; 1.0373x over previous
//
#include <hip/hip_runtime.h>
#include <math.h>

#define Tn 4096   // B*S tokens
#define Dn 2048   // hidden
#define Sn 2048   // seq
#define Hn 16     // heads
#define Fn 8192   // ffn
#define Rn 32     // adapter rank
#define FC 2048   // ffn chunk size

typedef short bf16x8 __attribute__((ext_vector_type(8)));
typedef float f32x4 __attribute__((ext_vector_type(4)));

union U8 { unsigned short s[8]; uint4 v; };

__device__ __forceinline__ float gelu_f(float x) {
  return 0.5f * x * (1.0f + tanhf(0.7978845608028654f * (x + 0.044715f * x * x * x)));
}

__device__ __forceinline__ unsigned short f2bf(float x) {   // RNE
  union { float f; unsigned u; } v; v.f = x;
  unsigned r = v.u + 0x7FFFu + ((v.u >> 16) & 1u);
  return (unsigned short)(r >> 16);
}
__device__ __forceinline__ float bf2f(unsigned short h) {
  union { unsigned u; float f; } v; v.u = ((unsigned)h) << 16; return v.f;
}

__device__ __forceinline__ void glds16(const unsigned short* g, unsigned short* lds) {
  __builtin_amdgcn_global_load_lds((const __attribute__((address_space(1))) void*)g,
                                   (__attribute__((address_space(3))) void*)lds, 16, 0, 0);
}

// ---------------- fused LayerNorm (+ optional router argmax), bf16 hi/lo output --------
// mcnt: optional device row count (compact mode) - blocks >= *mcnt exit
__global__ __launch_bounds__(256)
void ln_router_kernel(const float* __restrict__ x,
                      const float* __restrict__ sc,
                      const float* __restrict__ bi,
                      const float* __restrict__ wr,
                      unsigned short* __restrict__ xh,
                      unsigned short* __restrict__ xl,
                      int* __restrict__ dec,
                      const int* __restrict__ mcnt)
{
  const int t = blockIdx.x;
  if (mcnt && t >= *mcnt) return;
  const int tid = threadIdx.x;
  const float* row = x + (size_t)t * Dn;
  const int d0 = tid * 8;
  float4 v0 = *(const float4*)(row + d0);
  float4 v1 = *(const float4*)(row + d0 + 4);
  float a[5];
  a[0] = v0.x + v0.y + v0.z + v0.w + v1.x + v1.y + v1.z + v1.w;
  a[1] = v0.x*v0.x + v0.y*v0.y + v0.z*v0.z + v0.w*v0.w
       + v1.x*v1.x + v1.y*v1.y + v1.z*v1.z + v1.w*v1.w;
  a[2] = 0.f; a[3] = 0.f; a[4] = 0.f;
  if (wr) {
#pragma unroll
    for (int r = 0; r < 3; ++r) {
      float4 w0 = *(const float4*)(wr + r * Dn + d0);
      float4 w1 = *(const float4*)(wr + r * Dn + d0 + 4);
      a[2 + r] = v0.x*w0.x + v0.y*w0.y + v0.z*w0.z + v0.w*w0.w
               + v1.x*w1.x + v1.y*w1.y + v1.z*w1.z + v1.w*w1.w;
    }
  }
#pragma unroll
  for (int i = 0; i < 5; ++i) {
#pragma unroll
    for (int off = 32; off > 0; off >>= 1)
      a[i] += __shfl_down(a[i], off);
  }
  __shared__ float red[4][5];
  __shared__ float fin[5];
  const int wv = tid >> 6, ln = tid & 63;
  if (ln == 0) {
#pragma unroll
    for (int i = 0; i < 5; ++i) red[wv][i] = a[i];
  }
  __syncthreads();
  if (tid == 0) {
#pragma unroll
    for (int i = 0; i < 5; ++i)
      fin[i] = red[0][i] + red[1][i] + red[2][i] + red[3][i];
    if (dec) {
      float l0 = fin[2], l1 = fin[3], l2 = fin[4];
      int best = 0; float bl = l0;
      if (l1 > bl) { best = 1; bl = l1; }
      if (l2 > bl) { best = 2; }
      dec[t] = best;
    }
  }
  __syncthreads();
  const float mu  = fin[0] * (1.0f / Dn);
  const float var = fin[1] * (1.0f / Dn) - mu * mu;
  const float rs  = rsqrtf(var + 1e-5f);
  float4 s0 = *(const float4*)(sc + d0);
  float4 s1 = *(const float4*)(sc + d0 + 4);
  float4 b0 = *(const float4*)(bi + d0);
  float4 b1 = *(const float4*)(bi + d0 + 4);
  float o[8];
  o[0] = (v0.x - mu) * rs * s0.x + b0.x;
  o[1] = (v0.y - mu) * rs * s0.y + b0.y;
  o[2] = (v0.z - mu) * rs * s0.z + b0.z;
  o[3] = (v0.w - mu) * rs * s0.w + b0.w;
  o[4] = (v1.x - mu) * rs * s1.x + b1.x;
  o[5] = (v1.y - mu) * rs * s1.y + b1.y;
  o[6] = (v1.z - mu) * rs * s1.z + b1.z;
  o[7] = (v1.w - mu) * rs * s1.w + b1.w;
  U8 hu, lu;
#pragma unroll
  for (int j = 0; j < 8; ++j) {
    hu.s[j] = f2bf(o[j]);
    lu.s[j] = f2bf(o[j] - bf2f(hu.s[j]));
  }
  *(uint4*)&xh[(size_t)t * Dn + d0] = hu.v;
  *(uint4*)&xl[(size_t)t * Dn + d0] = lu.v;
}

// ---------------- route compaction: idx2 = tokens with dec==2 (order-free) ----------
__global__ __launch_bounds__(256)
void compact_kernel(const int* __restrict__ dec, int* __restrict__ idx2,
                    int* __restrict__ n2)
{
  int t = blockIdx.x * 256 + threadIdx.x;
  if (t >= Tn) return;
  if (dec[t] == 2) {
    int pos = atomicAdd(n2, 1);
    idx2[pos] = t;
  }
}

// ---------------- fp32 -> bf16 hi/lo pair (weights) ----------------
__global__ __launch_bounds__(256)
void cvt_pair_kernel(const float* __restrict__ src, int ld, int K,
                     unsigned short* __restrict__ H, unsigned short* __restrict__ L,
                     int total8)
{
  int i = blockIdx.x * 256 + threadIdx.x;
  if (i >= total8) return;
  size_t e = (size_t)i * 8;
  int row = (int)(e / (size_t)K);
  int col = (int)(e % (size_t)K);
  const float* s = src + (size_t)row * ld + col;
  float4 v0 = *(const float4*)s;
  float4 v1 = *(const float4*)(s + 4);
  float o[8] = {v0.x, v0.y, v0.z, v0.w, v1.x, v1.y, v1.z, v1.w};
  U8 hu, lu;
#pragma unroll
  for (int j = 0; j < 8; ++j) {
    hu.s[j] = f2bf(o[j]);
    lu.s[j] = f2bf(o[j] - bf2f(hu.s[j]));
  }
  *(uint4*)&H[e] = hu.v;
  *(uint4*)&L[e] = lu.v;
}

// ---------------- split-bf16 MFMA GEMM: C = (Ah+Al)[M,K] @ (Bh+Bl)[N,K]^T ----------------
// mode bits: 1=gelu+pair-out, 4=plain pair-out, 2=fp32 accumulate, 0=fp32 (+resid)
// Compact support: mcnt = device row count (blocks beyond exit, partial rows guarded);
// arow = gather index for A rows & resid rows; crow = scatter index for C rows.
#define BM 128
#define BN 128
#define BK 32
__global__ __launch_bounds__(256)
void gemm_bf16s(const unsigned short* __restrict__ Ah, const unsigned short* __restrict__ Al,
                const unsigned short* __restrict__ Bh, const unsigned short* __restrict__ Bl,
                int K, float* __restrict__ C, const float* __restrict__ resid,
                unsigned short* __restrict__ Gh, unsigned short* __restrict__ Gl,
                int N, int mode,
                const int* __restrict__ arow, const int* __restrict__ crow,
                const int* __restrict__ mcnt)
{
  __shared__ unsigned short sAh[BM * BK];
  __shared__ unsigned short sAl[BM * BK];
  __shared__ unsigned short sBh[BN * BK];
  __shared__ unsigned short sBl[BN * BK];
  const int tid = threadIdx.x;
  const int l = tid & 63, w = tid >> 6;
  const int wm = w >> 1, wn = w & 1;
  const int fr = l & 15, kg = (l >> 4) * 8;
  const int bm = blockIdx.y * BM, bn = blockIdx.x * BN;
  const int M2 = mcnt ? *mcnt : (1 << 30);
  if (bm >= M2) return;

  // per-thread A source rows for the two staging passes (clamped for partial tail)
  int asrc[2];
#pragma unroll
  for (int r = 0; r < 2; ++r) {
    int rr = bm + ((r * 256 + tid) >> 2);
    if (rr >= M2) rr = M2 - 1;
    asrc[r] = arow ? arow[rr] : rr;
  }

  f32x4 acc[4][4];
#pragma unroll
  for (int m = 0; m < 4; ++m)
#pragma unroll
    for (int n = 0; n < 4; ++n)
#pragma unroll
      for (int q = 0; q < 4; ++q) acc[m][n][q] = 0.f;

  for (int k0 = 0; k0 < K; k0 += BK) {
#pragma unroll
    for (int r = 0; r < 2; ++r) {
      const int c = r * 256 + tid;
      const int row = c >> 2, q = c & 3;
      const size_t ga = (size_t)asrc[r] * K + k0 + q * 8;
      const size_t gb = (size_t)(bn + row) * K + k0 + q * 8;
      const int ub = (r * 256 + w * 64) * 8;
      glds16(Ah + ga, sAh + ub);
      glds16(Al + ga, sAl + ub);
      glds16(Bh + gb, sBh + ub);
      glds16(Bl + gb, sBl + ub);
    }
    __syncthreads();

    bf16x8 ah[4], al[4], bh[4], bl[4];
#pragma unroll
    for (int m = 0; m < 4; ++m) {
      const int ro = (wm * 64 + m * 16 + fr) * BK + kg;
      ah[m] = *(const bf16x8*)&sAh[ro];
      al[m] = *(const bf16x8*)&sAl[ro];
    }
#pragma unroll
    for (int n = 0; n < 4; ++n) {
      const int ro = (wn * 64 + n * 16 + fr) * BK + kg;
      bh[n] = *(const bf16x8*)&sBh[ro];
      bl[n] = *(const bf16x8*)&sBl[ro];
    }
#pragma unroll
    for (int m = 0; m < 4; ++m)
#pragma unroll
      for (int n = 0; n < 4; ++n) {
        acc[m][n] = __builtin_amdgcn_mfma_f32_16x16x32_bf16(ah[m], bh[n], acc[m][n], 0, 0, 0);
        acc[m][n] = __builtin_amdgcn_mfma_f32_16x16x32_bf16(ah[m], bl[n], acc[m][n], 0, 0, 0);
        acc[m][n] = __builtin_amdgcn_mfma_f32_16x16x32_bf16(al[m], bh[n], acc[m][n], 0, 0, 0);
      }
    __syncthreads();
  }

  const int rbase = (l >> 4) * 4;
#pragma unroll
  for (int m = 0; m < 4; ++m) {
#pragma unroll
    for (int i = 0; i < 4; ++i) {
      const int rl = wm * 64 + m * 16 + rbase + i;
      const int rr = bm + rl;
      if (rr >= M2) continue;
      const int cr = crow ? crow[rr] : rr;
      const int ar = arow ? arow[rr] : rr;
#pragma unroll
      for (int n = 0; n < 4; ++n) {
        const int col = bn + wn * 64 + n * 16 + fr;
        float v = acc[m][n][i];
        const size_t idxc = (size_t)cr * N + col;
        if (mode & 5) {               // pair output (1 => gelu first)
          float g = (mode & 1) ? gelu_f(v) : v;
          unsigned short h = f2bf(g);
          Gh[idxc] = h;
          Gl[idxc] = f2bf(g - bf2f(h));
        } else {
          if (resid) v += resid[(size_t)ar * N + col];
          if (mode & 2) v += C[idxc];
          C[idxc] = v;
        }
      }
    }
  }
}

// ---------------- fp32 vector GEMM (adapter only) ----------------
#define GBM 128
#define GBN 128
#define GBK 16
__global__ __launch_bounds__(256)
void gemm_nt(const float* __restrict__ A, int lda,
             const float* __restrict__ B, int ldb,
             float* __restrict__ C, int ldc,
             const float* __restrict__ resid,
             int M, int N, int K, int flags)
{
  __shared__ float As[GBK][GBM + 4];
  __shared__ float Bs[GBK][GBN + 4];
  const int bm = blockIdx.y * GBM;
  const int bn = blockIdx.x * GBN;
  const int tid = threadIdx.x;
  const int ty = tid >> 4, tx = tid & 15;
  float acc[8][8];
#pragma unroll
  for (int i = 0; i < 8; ++i)
#pragma unroll
    for (int j = 0; j < 8; ++j) acc[i][j] = 0.f;

  for (int k0 = 0; k0 < K; k0 += GBK) {
#pragma unroll
    for (int i = 0; i < 2; ++i) {
      int fid = tid + i * 256;
      int row = fid >> 2, c = (fid & 3) << 2;
      float4 av = *(const float4*)(A + (size_t)(bm + row) * lda + k0 + c);
      As[c + 0][row] = av.x; As[c + 1][row] = av.y;
      As[c + 2][row] = av.z; As[c + 3][row] = av.w;
      float4 bv = make_float4(0.f, 0.f, 0.f, 0.f);
      if (bn + row < N)
        bv = *(const float4*)(B + (size_t)(bn + row) * ldb + k0 + c);
      Bs[c + 0][row] = bv.x; Bs[c + 1][row] = bv.y;
      Bs[c + 2][row] = bv.z; Bs[c + 3][row] = bv.w;
    }
    __syncthreads();
#pragma unroll
    for (int k = 0; k < GBK; ++k) {
      float4 a0 = *(const float4*)&As[k][ty * 4];
      float4 a1 = *(const float4*)&As[k][64 + ty * 4];
      float4 b0 = *(const float4*)&Bs[k][tx * 4];
      float4 b1 = *(const float4*)&Bs[k][64 + tx * 4];
      float aa[8] = {a0.x, a0.y, a0.z, a0.w, a1.x, a1.y, a1.z, a1.w};
      float bb[8] = {b0.x, b0.y, b0.z, b0.w, b1.x, b1.y, b1.z, b1.w};
#pragma unroll
      for (int i = 0; i < 8; ++i)
#pragma unroll
        for (int j = 0; j < 8; ++j)
          acc[i][j] += aa[i] * bb[j];
    }
    __syncthreads();
  }
#pragma unroll
  for (int i = 0; i < 8; ++i) {
    int row = bm + ((i < 4) ? (ty * 4 + i) : (64 + ty * 4 + i - 4));
#pragma unroll
    for (int jj = 0; jj < 2; ++jj) {
      int col = bn + ((jj == 0) ? (tx * 4) : (64 + tx * 4));
      if (col < N) {
        float4 o;
        o.x = acc[i][jj * 4 + 0]; o.y = acc[i][jj * 4 + 1];
        o.z = acc[i][jj * 4 + 2]; o.w = acc[i][jj * 4 + 3];
        if (flags & 1) { o.x = gelu_f(o.x); o.y = gelu_f(o.y); o.z = gelu_f(o.z); o.w = gelu_f(o.w); }
        size_t cidx = (size_t)row * ldc + col;
        if (resid) {
          float4 rv = *(const float4*)(resid + cidx);
          o.x += rv.x; o.y += rv.y; o.z += rv.z; o.w += rv.w;
        }
        if (flags & 2) {
          float4 cv = *(const float4*)(C + cidx);
          o.x += cv.x; o.y += cv.y; o.z += cv.z; o.w += cv.w;
        }
        *(float4*)(C + cidx) = o;
      }
    }
  }
}

// ---------------- per-head V transpose: [B,S,H*128] pair -> [B*H,128,S] pair ----------
__global__ __launch_bounds__(256)
void vtrans_kernel(const unsigned short* __restrict__ Vh, const unsigned short* __restrict__ Vl,
                   unsigned short* __restrict__ Th, unsigned short* __restrict__ Tl)
{
  __shared__ unsigned short T[64][68];
  const int j0 = blockIdx.x * 64;
  const int d0 = blockIdx.y * 64;
  const int bh = blockIdx.z;
  const int b = bh >> 4, h = bh & 15;
  const int tid = threadIdx.x;
  const int jr = tid >> 2, cc = (tid & 3) * 16;   // load: row j0+jr, cols d0+cc..+15
  const size_t inrow = ((size_t)b * Sn + j0 + jr) * Dn + h * 128 + d0 + cc;
  const int dr = tid >> 2, jc = (tid & 3) * 16;   // store: row d0+dr, cols j0+jc..+15
  const size_t outrow = ((size_t)bh * 128 + d0 + dr) * (size_t)Sn + j0 + jc;
#pragma unroll
  for (int pass = 0; pass < 2; ++pass) {
    const unsigned short* src = pass ? Vl : Vh;
    unsigned short* dst = pass ? Tl : Th;
    ushort4 u[4];
#pragma unroll
    for (int c = 0; c < 4; ++c) u[c] = *(const ushort4*)&src[inrow + c * 4];
    if (pass) __syncthreads();                    // pass-0 reads done before overwrite
#pragma unroll
    for (int c = 0; c < 4; ++c) {
      T[cc + c*4 + 0][jr] = u[c].x;
      T[cc + c*4 + 1][jr] = u[c].y;
      T[cc + c*4 + 2][jr] = u[c].z;
      T[cc + c*4 + 3][jr] = u[c].w;
    }
    __syncthreads();
#pragma unroll
    for (int c = 0; c < 4; ++c)
      *(ushort4*)&dst[outrow + c * 4] = *(const ushort4*)&T[dr][jc + c * 4];
  }
}

// ---------------- MFMA causal flash attention (split-bf16), 1 wave/block ----------------
// grid (Sn/16, B*Hn), 64 thr = 1 wave handling 16 q rows. LPT: largest q0 first.
// Fragment conventions identical to gemm_bf16s (HW-validated rounds 4 & 8):
//   A-frag: lane holds A[row=l&15][k=(l>>4)*8+i];  B-frag: B[col=l&15][k=(l>>4)*8+i]
//   D: row=(l>>4)*4+i (A side), col=l&15 (B side)
__global__ __launch_bounds__(64, 4)
void attn_mfma(const unsigned short* __restrict__ Qh, const unsigned short* __restrict__ Ql,
               const unsigned short* __restrict__ Kh, const unsigned short* __restrict__ Kl,
               const unsigned short* __restrict__ Vth, const unsigned short* __restrict__ Vtl,
               unsigned short* __restrict__ Ch, unsigned short* __restrict__ Cl)
{
  const int bh = blockIdx.y;
  const int b = bh >> 4, h = bh & 15;
  // LPT: reverse mapping so longest blocks (largest q0) dispatch first
  const int qt = (gridDim.x - 1) - blockIdx.x;
  const int q0w = qt * 16;
  const int l = threadIdx.x & 63;
  const int lr = l & 15, lg = l >> 4;
  const float scl = 0.08838834764831845f;   // 1/sqrt(128)

  // Q A-fragments (row = q0w+lr), 128 dims = 4 k-steps, hi+lo
  const size_t qrow = ((size_t)b * Sn + q0w + lr) * (size_t)Dn + h * 128;
  bf16x8 qfh[4], qfl[4];
#pragma unroll
  for (int ks = 0; ks < 4; ++ks) {
    qfh[ks] = *(const bf16x8*)&Qh[qrow + ks * 32 + lg * 8];
    qfl[ks] = *(const bf16x8*)&Ql[qrow + ks * 32 + lg * 8];
  }

  f32x4 cacc[8];                       // cacc[dt][i] = ctx[q=q0w+lg*4+i][d=dt*16+lr]
#pragma unroll
  for (int dt = 0; dt < 8; ++dt)
#pragma unroll
    for (int i = 0; i < 4; ++i) cacc[dt][i] = 0.f;
  float mrun[4], lrun[4];
#pragma unroll
  for (int i = 0; i < 4; ++i) { mrun[i] = -1e30f; lrun[i] = 0.f; }

  __shared__ unsigned short ph[512];   // wave-private P hi [16q][32j]
  __shared__ unsigned short pl[512];

  const size_t krowbase = (size_t)b * Sn * Dn + h * 128;
  const size_t vtbase = (size_t)bh * 128 * (size_t)Sn;
  const int ntw = (q0w + 15) / 32 + 1;     // tiles with j0 <= q0w+15

  for (int t = 0; t < ntw; ++t) {
    const int j0 = t * 32;
    // ---- scores: S[16q][32j], 3-pass split, 24 mfma ----
    f32x4 s0 = {0.f, 0.f, 0.f, 0.f}, s1 = {0.f, 0.f, 0.f, 0.f};
    const size_t kr0 = krowbase + (size_t)(j0 + lr) * Dn;
    const size_t kr1 = krowbase + (size_t)(j0 + 16 + lr) * Dn;
#pragma unroll
    for (int ks = 0; ks < 4; ++ks) {
      bf16x8 kh0 = *(const bf16x8*)&Kh[kr0 + ks * 32 + lg * 8];
      bf16x8 kl0 = *(const bf16x8*)&Kl[kr0 + ks * 32 + lg * 8];
      s0 = __builtin_amdgcn_mfma_f32_16x16x32_bf16(qfh[ks], kh0, s0, 0, 0, 0);
      s0 = __builtin_amdgcn_mfma_f32_16x16x32_bf16(qfl[ks], kh0, s0, 0, 0, 0);
      s0 = __builtin_amdgcn_mfma_f32_16x16x32_bf16(qfh[ks], kl0, s0, 0, 0, 0);
      bf16x8 kh1 = *(const bf16x8*)&Kh[kr1 + ks * 32 + lg * 8];
      bf16x8 kl1 = *(const bf16x8*)&Kl[kr1 + ks * 32 + lg * 8];
      s1 = __builtin_amdgcn_mfma_f32_16x16x32_bf16(qfh[ks], kh1, s1, 0, 0, 0);
      s1 = __builtin_amdgcn_mfma_f32_16x16x32_bf16(qfl[ks], kh1, s1, 0, 0, 0);
      s1 = __builtin_amdgcn_mfma_f32_16x16x32_bf16(qfh[ks], kl1, s1, 0, 0, 0);
    }
    // ---- online softmax (per lane: 4 q-rows, j = j0+{lr, 16+lr}) ----
    float p0a[4], p1a[4], cor[4];
#pragma unroll
    for (int i = 0; i < 4; ++i) {
      const int qg = q0w + lg * 4 + i;
      float a0 = s0[i] * scl; if (j0 + lr > qg) a0 = -1e30f;
      float a1 = s1[i] * scl; if (j0 + 16 + lr > qg) a1 = -1e30f;
      float mx = fmaxf(a0, a1);
      mx = fmaxf(mx, __shfl_xor(mx, 1));
      mx = fmaxf(mx, __shfl_xor(mx, 2));
      mx = fmaxf(mx, __shfl_xor(mx, 4));
      mx = fmaxf(mx, __shfl_xor(mx, 8));
      const float mt = fmaxf(mrun[i], mx);
      cor[i] = __expf(mrun[i] - mt);
      mrun[i] = mt;
      float p0 = __expf(a0 - mt);
      float p1 = __expf(a1 - mt);
      p0a[i] = p0; p1a[i] = p1;
      float ls = p0 + p1;
      ls += __shfl_xor(ls, 1);
      ls += __shfl_xor(ls, 2);
      ls += __shfl_xor(ls, 4);
      ls += __shfl_xor(ls, 8);
      lrun[i] = lrun[i] * cor[i] + ls;
    }
    // ---- P -> bf16 pair via wave-private LDS (layout transpose to A-frag) ----
#pragma unroll
    for (int i = 0; i < 4; ++i) {
      const int qrl = (lg * 4 + i) * 32;
      unsigned short h0 = f2bf(p0a[i]);
      ph[qrl + lr] = h0;
      pl[qrl + lr] = f2bf(p0a[i] - bf2f(h0));
      unsigned short h1 = f2bf(p1a[i]);
      ph[qrl + 16 + lr] = h1;
      pl[qrl + 16 + lr] = f2bf(p1a[i] - bf2f(h1));
    }
    // ---- rescale ctx ----
#pragma unroll
    for (int dt = 0; dt < 8; ++dt)
#pragma unroll
      for (int i = 0; i < 4; ++i) cacc[dt][i] *= cor[i];
    // ---- PV: 3-pass split, 24 mfma; A=P (from LDS), B=V^T rows (global) ----
    bf16x8 pah = *(const bf16x8*)&ph[lr * 32 + lg * 8];
    bf16x8 pal = *(const bf16x8*)&pl[lr * 32 + lg * 8];
#pragma unroll
    for (int dt = 0; dt < 8; ++dt) {
      const size_t vrow = vtbase + (size_t)(dt * 16 + lr) * Sn + j0 + lg * 8;
      bf16x8 vh = *(const bf16x8*)&Vth[vrow];
      bf16x8 vl = *(const bf16x8*)&Vtl[vrow];
      cacc[dt] = __builtin_amdgcn_mfma_f32_16x16x32_bf16(pah, vh, cacc[dt], 0, 0, 0);
      cacc[dt] = __builtin_amdgcn_mfma_f32_16x16x32_bf16(pah, vl, cacc[dt], 0, 0, 0);
      cacc[dt] = __builtin_amdgcn_mfma_f32_16x16x32_bf16(pal, vh, cacc[dt], 0, 0, 0);
    }
  }
  // ---- epilogue: normalize, split, store ctx pair ----
#pragma unroll
  for (int i = 0; i < 4; ++i) {
    const float inv = 1.0f / lrun[i];
    const size_t obase = ((size_t)b * Sn + q0w + lg * 4 + i) * Dn + h * 128 + lr;
#pragma unroll
    for (int dt = 0; dt < 8; ++dt) {
      float v = cacc[dt][i] * inv;
      unsigned short hh = f2bf(v);
      Ch[obase + dt * 16] = hh;
      Cl[obase + dt * 16] = f2bf(v - bf2f(hh));
    }
  }
}

// ---------------- final per-token routing fixup (out2 already in d_out) ----------------
__global__ __launch_bounds__(256)
void select_kernel(const float* __restrict__ h, const float* __restrict__ bias,
                   const float* __restrict__ out1,
                   const int* __restrict__ dec, float* __restrict__ out)
{
  int i = blockIdx.x * 256 + threadIdx.x;
  if (i >= Tn * Dn / 4) return;
  int t = i >> 9;
  int de = dec[t];
  if (de == 2) return;
  int d4 = (i & 511) << 2;
  size_t idx = (size_t)t * Dn + d4;
  float4 o;
  if (de == 0) {
    float4 hv = *(const float4*)(h + idx);
    float4 bv = *(const float4*)(bias + d4);
    o.x = hv.x + bv.x; o.y = hv.y + bv.y; o.z = hv.z + bv.z; o.w = hv.w + bv.w;
  } else {
    o = *(const float4*)(out1 + idx);
  }
  *(float4*)(out + idx) = o;
}

extern "C" void kernel_launch(void* const* d_in, const int* in_sizes, int n_in,
                              void* d_out, int out_size, void* d_ws, size_t ws_size,
                              hipStream_t stream) {
  const float* hid    = (const float*)d_in[0];
  const float* sbias  = (const float*)d_in[1];
  const float* w_down = (const float*)d_in[2];
  const float* w_up   = (const float*)d_in[3];
  const float* w_rout = (const float*)d_in[4];
  const float* ln1s   = (const float*)d_in[5];
  const float* ln1b   = (const float*)d_in[6];
  const float* wq     = (const float*)d_in[7];
  const float* wk     = (const float*)d_in[8];
  const float* wv     = (const float*)d_in[9];
  const float* wo     = (const float*)d_in[10];
  const float* ln2s   = (const float*)d_in[11];
  const float* ln2b   = (const float*)d_in[12];
  const float* w_ff1  = (const float*)d_in[13];
  const float* w_ff2  = (const float*)d_in[14];

  const size_t TD  = (size_t)Tn * Dn;           // 8M elems
  const size_t WEL = (size_t)Dn * FC;           // 4M elems

  // ---- workspace (aliased by liveness; ~144.6 MB) ----
  char* p = (char*)d_ws;
  auto alloc = [&](size_t bytes) -> char* {
    char* r = p; p += (bytes + 255) & ~(size_t)255; return r;
  };
  unsigned short* P1h = (unsigned short*)alloc(TD * 2);  // xn -> ctx -> xn2c (hi)
  unsigned short* P1l = (unsigned short*)alloc(TD * 2);
  unsigned short* B2  = (unsigned short*)alloc(TD * 2);  // Vh -> Qh -> x2c(half)
  unsigned short* B3  = (unsigned short*)alloc(TD * 2);  // Vl -> Ql -> x2c(half)
  unsigned short* B4  = (unsigned short*)alloc(TD * 2);  // Kh -> gelu hi (compact)
  unsigned short* B5  = (unsigned short*)alloc(TD * 2);  // Kl -> gelu lo (compact)
  unsigned short* B6  = (unsigned short*)alloc(TD * 2);  // Vth -> out1(half)
  unsigned short* B7  = (unsigned short*)alloc(TD * 2);  // Vtl -> out1(half)
  unsigned short* Wh  = (unsigned short*)alloc(WEL * 2);
  unsigned short* Wl  = (unsigned short*)alloc(WEL * 2);
  float* hd = (float*)alloc((size_t)Tn * Rn * 4);
  int* dec  = (int*)alloc((size_t)Tn * 4);
  int* idx2 = (int*)alloc((size_t)Tn * 4);
  int* n2d  = (int*)alloc(256);
  if ((size_t)(p - (char*)d_ws) > ws_size) return;

  unsigned short *Vh = B2, *Vl = B3;            // pre-transpose V pair
  unsigned short *Qh = B2, *Ql = B3;            // after vtrans
  unsigned short *Kh = B4, *Kl = B5;
  unsigned short *Vth = B6, *Vtl = B7;
  float* x2c  = (float*)B2;                     // compact x2 spans B2+B3 (Q dead)
  unsigned short *Gh = B4, *Gl = B5;            // K dead after attn (compact gelu)
  float* out1 = (float*)B6;                     // Vt dead after attn
  float* out2 = (float*)d_out;

  const int cw = (int)(WEL / 8 / 256);
  dim3 gq(Dn / BN, Tn / BM);

  // 1. LN1 + router; compaction list for path-2 tokens
  ln_router_kernel<<<Tn, 256, 0, stream>>>(hid, ln1s, ln1b, w_rout, P1h, P1l, dec, nullptr);
  hipMemsetAsync(n2d, 0, sizeof(int), stream);
  compact_kernel<<<Tn / 256, 256, 0, stream>>>(dec, idx2, n2d);
  // 2. V pair, then transpose per head
  cvt_pair_kernel<<<cw, 256, 0, stream>>>(wv, Dn, Dn, Wh, Wl, (int)(WEL / 8));
  gemm_bf16s<<<gq, 256, 0, stream>>>(P1h, P1l, Wh, Wl, Dn, nullptr, nullptr, Vh, Vl, Dn, 4,
                                     nullptr, nullptr, nullptr);
  vtrans_kernel<<<dim3(Sn / 64, 2, 2 * Hn), 256, 0, stream>>>(Vh, Vl, Vth, Vtl);
  // 3. Q, K pairs (Q overwrites V region - V already transposed)
  cvt_pair_kernel<<<cw, 256, 0, stream>>>(wq, Dn, Dn, Wh, Wl, (int)(WEL / 8));
  gemm_bf16s<<<gq, 256, 0, stream>>>(P1h, P1l, Wh, Wl, Dn, nullptr, nullptr, Qh, Ql, Dn, 4,
                                     nullptr, nullptr, nullptr);
  cvt_pair_kernel<<<cw, 256, 0, stream>>>(wk, Dn, Dn, Wh, Wl, (int)(WEL / 8));
  gemm_bf16s<<<gq, 256, 0, stream>>>(P1h, P1l, Wh, Wl, Dn, nullptr, nullptr, Kh, Kl, Dn, 4,
                                     nullptr, nullptr, nullptr);
  // 4. MFMA attention (1 wave/block, LPT order) -> ctx pair (xn dead)
  attn_mfma<<<dim3(Sn / 16, 2 * Hn), 64, 0, stream>>>(Qh, Ql, Kh, Kl, Vth, Vtl, P1h, P1l);
  // 5. x2c[r] = hid[idx2[r]] + ctx[idx2[r]] @ wo.T  (compact; only path-2 tokens)
  cvt_pair_kernel<<<cw, 256, 0, stream>>>(wo, Dn, Dn, Wh, Wl, (int)(WEL / 8));
  gemm_bf16s<<<gq, 256, 0, stream>>>(P1h, P1l, Wh, Wl, Dn, x2c, hid, nullptr, nullptr, Dn, 0,
                                     idx2, nullptr, n2d);
  // 6. xn2c = LN2(x2c) -> P1 pair (compact rows; ctx pair consumed)
  ln_router_kernel<<<Tn, 256, 0, stream>>>(x2c, ln2s, ln2b, nullptr, P1h, P1l, nullptr, n2d);
  // 7. FFN compact: d_out[idx2[r]] = x2c[r] + gelu(xn2c @ ff1.T) @ ff2.T
  for (int f0 = 0; f0 < Fn; f0 += FC) {
    cvt_pair_kernel<<<cw, 256, 0, stream>>>(w_ff1 + (size_t)f0 * Dn, Dn, Dn, Wh, Wl, (int)(WEL / 8));
    gemm_bf16s<<<gq, 256, 0, stream>>>(P1h, P1l, Wh, Wl, Dn, nullptr, nullptr, Gh, Gl, FC, 1,
                                       nullptr, nullptr, n2d);
    cvt_pair_kernel<<<cw, 256, 0, stream>>>(w_ff2 + f0, Fn, FC, Wh, Wl, (int)(WEL / 8));
    gemm_bf16s<<<gq, 256, 0, stream>>>(Gh, Gl, Wh, Wl, FC, out2,
                                       (f0 == 0) ? x2c : nullptr, nullptr, nullptr, Dn,
                                       (f0 == 0) ? 0 : 2,
                                       nullptr, idx2, n2d);
  }
  // 8. adapter: out1 = hid + (hid @ w_down.T) @ w_up.T
  gemm_nt<<<dim3(1, Tn / GBM), 256, 0, stream>>>(hid, Dn, w_down, Dn, hd, Rn, nullptr, Tn, Rn, Dn, 0);
  gemm_nt<<<dim3(Dn / GBN, Tn / GBM), 256, 0, stream>>>(hd, Rn, w_up, Rn, out1, Dn, hid, Tn, Dn, Rn, 0);
  // 9. routing fixup (path-0/1 tokens; path-2 rows already scattered into d_out)
  int nv4 = Tn * Dn / 4;
  select_kernel<<<(nv4 + 255) / 256, 256, 0, stream>>>(hid, sbias, out1, dec, (float*)d_out);
}